// Round 9
// baseline (434.593 us; speedup 1.0000x reference)
//
#include <hip/hip_runtime.h>

// RelativeAttention B=8, N=2048, D=512, fp32 in, (out[B,N,D], p[B,N,N]) fp32 out.
//
// Round-9: (1) score GEMMs use the counted-vmcnt depth-2 3-buffer gl_lds core
// (round-2 verbatim; exonerated by rounds-2/3 bit-identity). (2) softmax also
// emits ph = f16(p). (3) out_gemm reads A from ph in both K-loops (vector
// h16x4 loads in loop 1, u16 gather in loop 2, zero cvts) — bit-identical to
// round-8's cvt-at-LDS-write, so absmax must stay exactly 0.0859375.
// (ps/ProvOut — the remaining rounds-2..4 suspects — stay out of the build.)

#define SEQN 2048
#define DD   512
#define NB   8
#define WROWS 4095   // 2N-1
#define WPAD  4096   // padded row stride for wvT

typedef float     f32x4 __attribute__((ext_vector_type(4)));
typedef _Float16  h16x4 __attribute__((ext_vector_type(4)));
typedef _Float16  h16x8 __attribute__((ext_vector_type(8)));

__device__ __forceinline__ unsigned swzw(int row, int c4) {
  unsigned b = (unsigned)(row * 64 + c4 * 8);
  return b ^ (((unsigned)row & 6u) << 3);
}
__device__ __forceinline__ unsigned swzr(int row, int kg) {
  unsigned b = (unsigned)(row * 64 + kg * 16);
  return b ^ (((unsigned)row & 6u) << 3);
}

typedef const __attribute__((address_space(1))) unsigned int gu32_t;
typedef __attribute__((address_space(3))) unsigned int lu32_t;
__device__ __forceinline__ void gload_lds16(const void* g, void* l) {
  __builtin_amdgcn_global_load_lds((gu32_t*)g, (lu32_t*)l, 16, 0, 0);
}

// ---------------------------------------------------------------------------
// Counted-vmcnt depth-2 gl_lds core (round-2 verbatim, exonerated):
// 128x128 tile, 4 waves, K-step 32 (64 B/row f16), 3 LDS buffers of 16 KB
// (A at +0, B at +8192). vmcnt(8) = 2 tiles x 4 loads/wave in flight.
// ---------------------------------------------------------------------------
template <class P>
__device__ __forceinline__ void stage_tile(const P& prov, char* smem, int buf,
                                           int t, int wave, int l4, int cp) {
  char* lb = smem + buf * 16384;
#pragma unroll
  for (int h = 0; h < 2; h++) {
    int R = wave * 32 + h * 16;
    int row = R + l4;
    int c = cp ^ ((row >> 1) & 3);
    gload_lds16((const char*)prov.a_src(t, row) + c * 16, lb + R * 64);
    gload_lds16((const char*)prov.b_src(t, row) + c * 16, lb + 8192 + R * 64);
  }
}

template <int NT, class P>
__device__ __forceinline__ void gemm_core_cnt(const P& prov, char* smem, f32x4 (&acc)[4][4]) {
  const int tid = threadIdx.x;
  const int lane = tid & 63, wave = tid >> 6;
  const int l4 = lane >> 2, cp = lane & 3;
  const int wm = wave >> 1, wn = wave & 1;
  const int r16 = lane & 15, kg = lane >> 4;

  stage_tile(prov, smem, 0, 0, wave, l4, cp);
  stage_tile(prov, smem, 1, 1, wave, l4, cp);
  stage_tile(prov, smem, 2, 2, wave, l4, cp);

  int buf = 0;
  for (int t = 0; t < NT; t++) {
    asm volatile("s_waitcnt vmcnt(8)" ::: "memory");
    __builtin_amdgcn_s_barrier();
    char* lb = smem + buf * 16384;
    h16x8 af[4], bf[4];
#pragma unroll
    for (int mf = 0; mf < 4; mf++)
      af[mf] = *(const h16x8*)(lb + swzr(wm * 64 + mf * 16 + r16, kg));
#pragma unroll
    for (int nf = 0; nf < 4; nf++)
      bf[nf] = *(const h16x8*)(lb + 8192 + swzr(wn * 64 + nf * 16 + r16, kg));
#pragma unroll
    for (int mf = 0; mf < 4; mf++)
#pragma unroll
      for (int nf = 0; nf < 4; nf++)
        acc[mf][nf] = __builtin_amdgcn_mfma_f32_16x16x32_f16(af[mf], bf[nf], acc[mf][nf], 0, 0, 0);
    asm volatile("s_waitcnt lgkmcnt(0)" ::: "memory");
    __builtin_amdgcn_s_barrier();
    int nt2 = t + 3; if (nt2 >= NT) nt2 = NT - 1;   // clamped restage keeps vmcnt counting uniform
    stage_tile(prov, smem, buf, nt2, wave, l4, cp);
    buf = (buf == 2) ? 0 : buf + 1;
  }
}

// ---------------- providers -------------------------------------------------
struct ProvQK {   // base scores: A=q_h rows i, B=k_h rows j (stride 1024 B)
  const char *ar, *br;
  __device__ __forceinline__ const void* a_src(int t, int row) const {
    return ar + (size_t)row * 1024 + (size_t)t * 64;
  }
  __device__ __forceinline__ const void* b_src(int t, int row) const {
    return br + (size_t)row * 1024 + (size_t)t * 64;
  }
};
struct ProvRel {  // rel scores: A=q_h, B=wk_h band rows (clamped)
  const char *ar, *wk; int tb;
  __device__ __forceinline__ const void* a_src(int t, int row) const {
    return ar + (size_t)row * 1024 + (size_t)t * 64;
  }
  __device__ __forceinline__ const void* b_src(int t, int row) const {
    int tr = tb + row; if (tr > WROWS - 1) tr = WROWS - 1;
    return wk + (size_t)tr * 1024 + (size_t)t * 64;
  }
};

// ---------------- f32 -> f16 bulk convert -----------------------------------
__global__ __launch_bounds__(256) void cvt_f16_k(const float* __restrict__ in,
                                                 _Float16* __restrict__ out, long n8) {
  for (long i = (long)blockIdx.x * 256 + threadIdx.x; i < n8; i += (long)gridDim.x * 256) {
    f32x4 a = ((const f32x4*)in)[i * 2];
    f32x4 b = ((const f32x4*)in)[i * 2 + 1];
    h16x8 h = {(_Float16)a[0], (_Float16)a[1], (_Float16)a[2], (_Float16)a[3],
               (_Float16)b[0], (_Float16)b[1], (_Float16)b[2], (_Float16)b[3]};
    ((h16x8*)out)[i] = h;
  }
}

// ---------------- transpose v [B,N,D] f32 -> vT [B,D,N] f16 ----------------
__global__ __launch_bounds__(256) void transpose_v_k(const float* __restrict__ v,
                                                     _Float16* __restrict__ vT) {
  __shared__ float tile[32][33];
  const int d0 = blockIdx.x * 32, j0 = blockIdx.y * 32, b = blockIdx.z;
  const int tid = threadIdx.x;
#pragma unroll
  for (int rep = 0; rep < 4; rep++) {
    int idx = rep * 256 + tid;
    int rr = idx >> 5, cc = idx & 31;
    tile[rr][cc] = v[((size_t)(b * SEQN + j0 + rr)) * DD + d0 + cc];
  }
  __syncthreads();
#pragma unroll
  for (int rep = 0; rep < 4; rep++) {
    int idx = rep * 256 + tid;
    int rr = idx >> 5, cc = idx & 31;
    vT[((size_t)(b * DD + d0 + rr)) * SEQN + j0 + cc] = (_Float16)tile[cc][rr];
  }
}

// ------------- transpose w_v [4095,512] f32 -> wvT [512,4096] f16 -----------
__global__ __launch_bounds__(256) void transpose_wv_k(const float* __restrict__ wv,
                                                      _Float16* __restrict__ wvT) {
  __shared__ float tile[32][33];
  const int d0 = blockIdx.x * 32, r0 = blockIdx.y * 32;
  const int tid = threadIdx.x;
#pragma unroll
  for (int rep = 0; rep < 4; rep++) {
    int idx = rep * 256 + tid;
    int rr = idx >> 5, cc = idx & 31;
    float val = 0.f;
    if (r0 + rr < WROWS) val = wv[(size_t)(r0 + rr) * DD + d0 + cc];
    tile[rr][cc] = val;
  }
  __syncthreads();
#pragma unroll
  for (int rep = 0; rep < 4; rep++) {
    int idx = rep * 256 + tid;
    int rr = idx >> 5, cc = idx & 31;
    wvT[(size_t)(d0 + rr) * WPAD + r0 + cc] = (_Float16)tile[cc][rr];
  }
}

// ---------------- score kernels: counted-vmcnt gl_lds core ------------------
__global__ __launch_bounds__(256) void score_base2_k(const _Float16* __restrict__ qh,
                                                     const _Float16* __restrict__ kh,
                                                     float* __restrict__ S) {
  __shared__ __align__(16) char smem[49152];
  const int j0 = blockIdx.x * 128, i0 = blockIdx.y * 128, b = blockIdx.z;
  const int tid = threadIdx.x, lane = tid & 63, wave = tid >> 6;
  const int wm = wave >> 1, wn = wave & 1, r16 = lane & 15, kg = lane >> 4;

  f32x4 acc[4][4];
#pragma unroll
  for (int mf = 0; mf < 4; mf++)
#pragma unroll
    for (int nf = 0; nf < 4; nf++) acc[mf][nf] = (f32x4){0.f, 0.f, 0.f, 0.f};

  ProvQK prov{(const char*)(qh + (size_t)(b * SEQN + i0) * DD),
              (const char*)(kh + (size_t)(b * SEQN + j0) * DD)};
  gemm_core_cnt<16>(prov, smem, acc);

#pragma unroll
  for (int mf = 0; mf < 4; mf++)
#pragma unroll
    for (int nf = 0; nf < 4; nf++)
#pragma unroll
      for (int r = 0; r < 4; r++) {
        int ii = wm * 64 + mf * 16 + kg * 4 + r;
        int jj = wn * 64 + nf * 16 + r16;
        S[(size_t)(b * SEQN + i0 + ii) * SEQN + j0 + jj] = acc[mf][nf][r];
      }
}

__global__ __launch_bounds__(256) void score_rel2_k(const _Float16* __restrict__ qh,
                                                    const _Float16* __restrict__ wkh,
                                                    float* __restrict__ S) {
  __shared__ __align__(16) char smem[49152];
  const int z = blockIdx.x, i0 = blockIdx.y * 128, b = blockIdx.z;
  const int tid = threadIdx.x, lane = tid & 63, wave = tid >> 6;
  const int wm = wave >> 1, wn = wave & 1, r16 = lane & 15, kg = lane >> 4;
  const int tmin = SEQN - 128 - i0;

  f32x4 acc[4][4];
#pragma unroll
  for (int mf = 0; mf < 4; mf++)
#pragma unroll
    for (int nf = 0; nf < 4; nf++) acc[mf][nf] = (f32x4){0.f, 0.f, 0.f, 0.f};

  ProvRel prov{(const char*)(qh + (size_t)(b * SEQN + i0) * DD),
               (const char*)wkh, tmin + z * 128};
  gemm_core_cnt<16>(prov, smem, acc);

  // scatter-add: band col bc -> j = bc + i' - 127
#pragma unroll
  for (int mf = 0; mf < 4; mf++)
#pragma unroll
    for (int nf = 0; nf < 4; nf++) {
      int bcg = z * 128 + wn * 64 + nf * 16 + r16;
#pragma unroll
      for (int r = 0; r < 4; r++) {
        int ii = wm * 64 + mf * 16 + kg * 4 + r;
        int j = bcg + ii - 127;
        if (bcg <= 2174 && j >= 0 && j < SEQN)
          S[(size_t)(b * SEQN + i0 + ii) * SEQN + j] += acc[mf][nf][r];
      }
    }
}

// -------- softmax over rows of S (in place -> p) + ph = f16(p) sidecar ------
__global__ __launch_bounds__(256) void softmax_rows_k(float* __restrict__ S,
                                                      _Float16* __restrict__ ph) {
  const int wid = threadIdx.x >> 6, lane = threadIdx.x & 63;
  const size_t row = (size_t)blockIdx.x * 4 + wid;
  float* p = S + row * SEQN;
  _Float16* phr = ph + row * SEQN;
  f32x4 x[8];
  float m = -3.4e38f;
#pragma unroll
  for (int c = 0; c < 8; c++) {
    x[c] = *(const f32x4*)(p + c * 256 + lane * 4);
    m = fmaxf(m, fmaxf(fmaxf(x[c][0], x[c][1]), fmaxf(x[c][2], x[c][3])));
  }
#pragma unroll
  for (int off = 32; off > 0; off >>= 1) m = fmaxf(m, __shfl_xor(m, off));
  float s = 0.f;
#pragma unroll
  for (int c = 0; c < 8; c++)
#pragma unroll
    for (int e = 0; e < 4; e++) {
      x[c][e] = __expf(x[c][e] - m);
      s += x[c][e];
    }
#pragma unroll
  for (int off = 32; off > 0; off >>= 1) s += __shfl_xor(s, off);
  float inv = 1.f / s;
#pragma unroll
  for (int c = 0; c < 8; c++) {
    x[c][0] *= inv; x[c][1] *= inv; x[c][2] *= inv; x[c][3] *= inv;
    *(f32x4*)(p + c * 256 + lane * 4) = x[c];
    h16x4 h = {(_Float16)x[c][0], (_Float16)x[c][1], (_Float16)x[c][2], (_Float16)x[c][3]};
    *(h16x4*)(phr + c * 256 + lane * 4) = h;
  }
}

// ------- out = p.v + skew(p).w_v — A from ph (f16), zero cvts ---------------
// 132 K-steps: t in [0,64) = ph.v ; t in [64,132) = skew(ph).w_v.
// Reg-prefetch one step ahead; 2x16KB LDS double buffer; 1 barrier/step.
__global__ __launch_bounds__(256) void out_gemm4_k(const _Float16* __restrict__ ph,
                                                   const _Float16* __restrict__ vT,
                                                   const _Float16* __restrict__ wvT,
                                                   float* __restrict__ outp) {
  __shared__ __align__(16) char smem[32768];
  // XCD-aware decode: 4 d-tiles sharing (i0,b)'s p rows land on one XCD.
  const int bid = blockIdx.x;
  const int xcd = bid & 7, rr = bid >> 3;
  const int x = rr & 3, s8 = rr >> 2;
  const int sidx = xcd + 8 * s8;             // [0,128): (i-tile, b), bijective
  const int d0 = x * 128, i0 = (sidx & 15) * 128, b = sidx >> 4;
  const int tid = threadIdx.x, lane = tid & 63, wave = tid >> 6;
  const int wm = wave >> 1, wn = wave & 1, r16 = lane & 15, kg = lane >> 4;
  const int tmin = SEQN - 128 - i0;

  const _Float16* pb = ph + (size_t)(b * SEQN + i0) * SEQN;
  const _Float16* vb = vT + (size_t)(b * DD + d0) * SEQN;
  const _Float16* wb = wvT + (size_t)d0 * WPAD + tmin;

  f32x4 acc[4][4];
#pragma unroll
  for (int mf = 0; mf < 4; mf++)
#pragma unroll
    for (int nf = 0; nf < 4; nf++) acc[mf][nf] = (f32x4){0.f, 0.f, 0.f, 0.f};

  h16x4 rav[4], rbv[4];   // staged A and B fragments (both f16 now)

  auto LOADREGS = [&](int t) {
    if (t < 64) {
      const int k0 = t * 32;
#pragma unroll
      for (int rep = 0; rep < 4; rep++) {
        int f = rep * 256 + tid, row = f >> 3, c4 = f & 7;
        rav[rep] = *(const h16x4*)(pb + (size_t)row * SEQN + k0 + c4 * 4);
        rbv[rep] = *(const h16x4*)(vb + (size_t)row * SEQN + k0 + c4 * 4);
      }
    } else {
      const int k0 = (t - 64) * 32;
#pragma unroll
      for (int rep = 0; rep < 4; rep++) {
        int f = rep * 256 + tid, row = f >> 3, c4 = f & 7;
        int jb = k0 + c4 * 4 + row - 127;
        const _Float16* pr = pb + (size_t)row * SEQN;
        h16x4 v4;
#pragma unroll
        for (int e = 0; e < 4; e++) {
          int j = jb + e;
          v4[e] = (j >= 0 && j < SEQN) ? pr[j] : (_Float16)0.f;
        }
        rav[rep] = v4;
        rbv[rep] = *(const h16x4*)(wb + (size_t)row * WPAD + k0 + c4 * 4);
      }
    }
  };
  auto WRITE = [&](char* lb) {
#pragma unroll
    for (int rep = 0; rep < 4; rep++) {
      int f = rep * 256 + tid, row = f >> 3, c4 = f & 7;
      *(h16x4*)(lb + swzw(row, c4)) = rav[rep];
      *(h16x4*)(lb + 8192 + swzw(row, c4)) = rbv[rep];
    }
  };

  LOADREGS(0);
  WRITE(smem);
  LOADREGS(1);                 // tile 1 pending in regs
  __syncthreads();             // tile 0 visible

  for (int t = 0; t < 132; t++) {
    char* lb = smem + (t & 1) * 16384;
    if (t + 1 < 132) WRITE(smem + ((t + 1) & 1) * 16384);   // WAR-safe
    h16x8 af[4], bf[4];
#pragma unroll
    for (int mf = 0; mf < 4; mf++)
      af[mf] = *(const h16x8*)(lb + swzr(wm * 64 + mf * 16 + r16, kg));
#pragma unroll
    for (int nf = 0; nf < 4; nf++)
      bf[nf] = *(const h16x8*)(lb + 8192 + swzr(wn * 64 + nf * 16 + r16, kg));
    if (t + 2 < 132) LOADREGS(t + 2);                        // issue early
#pragma unroll
    for (int mf = 0; mf < 4; mf++)
#pragma unroll
      for (int nf = 0; nf < 4; nf++)
        acc[mf][nf] = __builtin_amdgcn_mfma_f32_16x16x32_f16(af[mf], bf[nf], acc[mf][nf], 0, 0, 0);
    __syncthreads();
  }

#pragma unroll
  for (int mf = 0; mf < 4; mf++)
#pragma unroll
    for (int nf = 0; nf < 4; nf++)
#pragma unroll
      for (int r = 0; r < 4; r++) {
        int ii = wm * 64 + mf * 16 + kg * 4 + r;
        int dd = wn * 64 + nf * 16 + r16;
        outp[(size_t)(b * SEQN + i0 + ii) * DD + d0 + dd] = acc[mf][nf][r];
      }
}

extern "C" void kernel_launch(void* const* d_in, const int* in_sizes, int n_in,
                              void* d_out, int out_size, void* d_ws, size_t ws_size,
                              hipStream_t stream) {
  const float* q  = (const float*)d_in[0];
  const float* k  = (const float*)d_in[1];
  const float* v  = (const float*)d_in[2];
  const float* wk = (const float*)d_in[3];
  const float* wv = (const float*)d_in[4];

  float* outp = (float*)d_out;
  float* S    = outp + (size_t)NB * SEQN * DD;   // p region of d_out doubles as S

  // ws layout (f16 elems): vT | wvT | qh | kh | wkh | ph  = 125.8 MB total
  const size_t nVT = (size_t)NB * DD * SEQN;     // 8388608
  const size_t nWV = (size_t)DD * WPAD;          // 2097152
  const size_t nQH = (size_t)NB * SEQN * DD;     // 8388608
  const size_t nWK = 2097152;                    // 4095*512 rounded up
  _Float16* vT  = (_Float16*)d_ws;
  _Float16* wvT = vT + nVT;
  _Float16* qh  = wvT + nWV;
  _Float16* kh  = qh + nQH;
  _Float16* wkh = kh + nQH;
  _Float16* ph  = wkh + nWK;

  cvt_f16_k<<<dim3(2048), 256, 0, stream>>>(q,  qh,  (long)(nQH / 8));
  cvt_f16_k<<<dim3(2048), 256, 0, stream>>>(k,  kh,  (long)(nQH / 8));
  cvt_f16_k<<<dim3(1024), 256, 0, stream>>>(wk, wkh, (long)((size_t)WROWS * DD / 8));
  transpose_v_k <<<dim3(DD / 32, SEQN / 32, NB), 256, 0, stream>>>(v, vT);
  transpose_wv_k<<<dim3(DD / 32, 128),           256, 0, stream>>>(wv, wvT);

  score_base2_k <<<dim3(SEQN / 128, SEQN / 128, NB), 256, 0, stream>>>(qh, kh, S);
  score_rel2_k  <<<dim3(17, SEQN / 128, NB),         256, 0, stream>>>(qh, wkh, S);
  softmax_rows_k<<<dim3(NB * SEQN / 4),              256, 0, stream>>>(S, ph);
  out_gemm4_k   <<<dim3(512),                        256, 0, stream>>>(ph, vT, wvT, outp);
}

// Round 11
// 421.904 us; speedup vs baseline: 1.0301x; 1.0301x over previous
//
#include <hip/hip_runtime.h>

// RelativeAttention B=8, N=2048, D=512, fp32 in, (out[B,N,D], p[B,N,N]) fp32 out.
//
// Round-11: verified-best configuration. Bisection verdict (r2-r4,r10): the
// ps/p_skew+ProvOut pair is the convicted component — permanently dropped.
// Components here, each bit-verified on hardware:
//   - cvt_f16 chain + gl_lds mechanics (r8, absmax 0.0859375)
//   - counted-vmcnt depth-2 score core (r9, 0.0859375)
//   - softmax + ph=f16(p) sidecar (r9, 0.0859375)
//   - out 2-phase reg-prefetch structure (r5/r6/r8)
// New (micro, inside verified structure): out loop-1 A reads ph (aligned
// h16x4, no cvt — r9-verified values); out loop-2 keeps r8's f32 gather but
// drops predicates for t in [68,128) where j=k0+c4*4+e+row-127 is provably
// in [1,2047] (min at t=68: 128-127=1; max at t=127: 2016+31+127-127=2047).

#define SEQN 2048
#define DD   512
#define NB   8
#define WROWS 4095   // 2N-1
#define WPAD  4096   // padded row stride for wvT

typedef float     f32x4 __attribute__((ext_vector_type(4)));
typedef _Float16  h16x4 __attribute__((ext_vector_type(4)));
typedef _Float16  h16x8 __attribute__((ext_vector_type(8)));

__device__ __forceinline__ unsigned swzw(int row, int c4) {
  unsigned b = (unsigned)(row * 64 + c4 * 8);
  return b ^ (((unsigned)row & 6u) << 3);
}
__device__ __forceinline__ unsigned swzr(int row, int kg) {
  unsigned b = (unsigned)(row * 64 + kg * 16);
  return b ^ (((unsigned)row & 6u) << 3);
}

typedef const __attribute__((address_space(1))) unsigned int gu32_t;
typedef __attribute__((address_space(3))) unsigned int lu32_t;
__device__ __forceinline__ void gload_lds16(const void* g, void* l) {
  __builtin_amdgcn_global_load_lds((gu32_t*)g, (lu32_t*)l, 16, 0, 0);
}

// ---------------------------------------------------------------------------
// Counted-vmcnt depth-2 gl_lds core (verified r9): 128x128 tile, 4 waves,
// K-step 32 (64 B/row f16), 3 LDS buffers of 16 KB (A at +0, B at +8192).
// vmcnt(8) = 2 tiles x 4 loads/wave in flight. Read-side XOR swizzle applied
// by pre-swizzling the per-lane GLOBAL source chunk (both-sides rule).
// ---------------------------------------------------------------------------
template <class P>
__device__ __forceinline__ void stage_tile(const P& prov, char* smem, int buf,
                                           int t, int wave, int l4, int cp) {
  char* lb = smem + buf * 16384;
#pragma unroll
  for (int h = 0; h < 2; h++) {
    int R = wave * 32 + h * 16;
    int row = R + l4;
    int c = cp ^ ((row >> 1) & 3);
    gload_lds16((const char*)prov.a_src(t, row) + c * 16, lb + R * 64);
    gload_lds16((const char*)prov.b_src(t, row) + c * 16, lb + 8192 + R * 64);
  }
}

template <int NT, class P>
__device__ __forceinline__ void gemm_core_cnt(const P& prov, char* smem, f32x4 (&acc)[4][4]) {
  const int tid = threadIdx.x;
  const int lane = tid & 63, wave = tid >> 6;
  const int l4 = lane >> 2, cp = lane & 3;
  const int wm = wave >> 1, wn = wave & 1;
  const int r16 = lane & 15, kg = lane >> 4;

  stage_tile(prov, smem, 0, 0, wave, l4, cp);
  stage_tile(prov, smem, 1, 1, wave, l4, cp);
  stage_tile(prov, smem, 2, 2, wave, l4, cp);

  int buf = 0;
  for (int t = 0; t < NT; t++) {
    asm volatile("s_waitcnt vmcnt(8)" ::: "memory");
    __builtin_amdgcn_s_barrier();
    char* lb = smem + buf * 16384;
    h16x8 af[4], bf[4];
#pragma unroll
    for (int mf = 0; mf < 4; mf++)
      af[mf] = *(const h16x8*)(lb + swzr(wm * 64 + mf * 16 + r16, kg));
#pragma unroll
    for (int nf = 0; nf < 4; nf++)
      bf[nf] = *(const h16x8*)(lb + 8192 + swzr(wn * 64 + nf * 16 + r16, kg));
#pragma unroll
    for (int mf = 0; mf < 4; mf++)
#pragma unroll
      for (int nf = 0; nf < 4; nf++)
        acc[mf][nf] = __builtin_amdgcn_mfma_f32_16x16x32_f16(af[mf], bf[nf], acc[mf][nf], 0, 0, 0);
    asm volatile("s_waitcnt lgkmcnt(0)" ::: "memory");
    __builtin_amdgcn_s_barrier();
    int nt2 = t + 3; if (nt2 >= NT) nt2 = NT - 1;   // clamped restage keeps vmcnt counting uniform
    stage_tile(prov, smem, buf, nt2, wave, l4, cp);
    buf = (buf == 2) ? 0 : buf + 1;
  }
}

// ---------------- providers -------------------------------------------------
struct ProvQK {   // base scores: A=q_h rows i, B=k_h rows j (stride 1024 B)
  const char *ar, *br;
  __device__ __forceinline__ const void* a_src(int t, int row) const {
    return ar + (size_t)row * 1024 + (size_t)t * 64;
  }
  __device__ __forceinline__ const void* b_src(int t, int row) const {
    return br + (size_t)row * 1024 + (size_t)t * 64;
  }
};
struct ProvRel {  // rel scores: A=q_h, B=wk_h band rows (clamped)
  const char *ar, *wk; int tb;
  __device__ __forceinline__ const void* a_src(int t, int row) const {
    return ar + (size_t)row * 1024 + (size_t)t * 64;
  }
  __device__ __forceinline__ const void* b_src(int t, int row) const {
    int tr = tb + row; if (tr > WROWS - 1) tr = WROWS - 1;
    return wk + (size_t)tr * 1024 + (size_t)t * 64;
  }
};

// ---------------- f32 -> f16 bulk convert -----------------------------------
__global__ __launch_bounds__(256) void cvt_f16_k(const float* __restrict__ in,
                                                 _Float16* __restrict__ out, long n8) {
  for (long i = (long)blockIdx.x * 256 + threadIdx.x; i < n8; i += (long)gridDim.x * 256) {
    f32x4 a = ((const f32x4*)in)[i * 2];
    f32x4 b = ((const f32x4*)in)[i * 2 + 1];
    h16x8 h = {(_Float16)a[0], (_Float16)a[1], (_Float16)a[2], (_Float16)a[3],
               (_Float16)b[0], (_Float16)b[1], (_Float16)b[2], (_Float16)b[3]};
    ((h16x8*)out)[i] = h;
  }
}

// ---------------- transpose v [B,N,D] f32 -> vT [B,D,N] f16 ----------------
__global__ __launch_bounds__(256) void transpose_v_k(const float* __restrict__ v,
                                                     _Float16* __restrict__ vT) {
  __shared__ float tile[32][33];
  const int d0 = blockIdx.x * 32, j0 = blockIdx.y * 32, b = blockIdx.z;
  const int tid = threadIdx.x;
#pragma unroll
  for (int rep = 0; rep < 4; rep++) {
    int idx = rep * 256 + tid;
    int rr = idx >> 5, cc = idx & 31;
    tile[rr][cc] = v[((size_t)(b * SEQN + j0 + rr)) * DD + d0 + cc];
  }
  __syncthreads();
#pragma unroll
  for (int rep = 0; rep < 4; rep++) {
    int idx = rep * 256 + tid;
    int rr = idx >> 5, cc = idx & 31;
    vT[((size_t)(b * DD + d0 + rr)) * SEQN + j0 + cc] = (_Float16)tile[cc][rr];
  }
}

// ------------- transpose w_v [4095,512] f32 -> wvT [512,4096] f16 -----------
__global__ __launch_bounds__(256) void transpose_wv_k(const float* __restrict__ wv,
                                                      _Float16* __restrict__ wvT) {
  __shared__ float tile[32][33];
  const int d0 = blockIdx.x * 32, r0 = blockIdx.y * 32;
  const int tid = threadIdx.x;
#pragma unroll
  for (int rep = 0; rep < 4; rep++) {
    int idx = rep * 256 + tid;
    int rr = idx >> 5, cc = idx & 31;
    float val = 0.f;
    if (r0 + rr < WROWS) val = wv[(size_t)(r0 + rr) * DD + d0 + cc];
    tile[rr][cc] = val;
  }
  __syncthreads();
#pragma unroll
  for (int rep = 0; rep < 4; rep++) {
    int idx = rep * 256 + tid;
    int rr = idx >> 5, cc = idx & 31;
    wvT[(size_t)(d0 + rr) * WPAD + r0 + cc] = (_Float16)tile[cc][rr];
  }
}

// ---------------- score kernels: counted-vmcnt gl_lds core ------------------
__global__ __launch_bounds__(256) void score_base2_k(const _Float16* __restrict__ qh,
                                                     const _Float16* __restrict__ kh,
                                                     float* __restrict__ S) {
  __shared__ __align__(16) char smem[49152];
  const int j0 = blockIdx.x * 128, i0 = blockIdx.y * 128, b = blockIdx.z;
  const int tid = threadIdx.x, lane = tid & 63, wave = tid >> 6;
  const int wm = wave >> 1, wn = wave & 1, r16 = lane & 15, kg = lane >> 4;

  f32x4 acc[4][4];
#pragma unroll
  for (int mf = 0; mf < 4; mf++)
#pragma unroll
    for (int nf = 0; nf < 4; nf++) acc[mf][nf] = (f32x4){0.f, 0.f, 0.f, 0.f};

  ProvQK prov{(const char*)(qh + (size_t)(b * SEQN + i0) * DD),
              (const char*)(kh + (size_t)(b * SEQN + j0) * DD)};
  gemm_core_cnt<16>(prov, smem, acc);

#pragma unroll
  for (int mf = 0; mf < 4; mf++)
#pragma unroll
    for (int nf = 0; nf < 4; nf++)
#pragma unroll
      for (int r = 0; r < 4; r++) {
        int ii = wm * 64 + mf * 16 + kg * 4 + r;
        int jj = wn * 64 + nf * 16 + r16;
        S[(size_t)(b * SEQN + i0 + ii) * SEQN + j0 + jj] = acc[mf][nf][r];
      }
}

__global__ __launch_bounds__(256) void score_rel2_k(const _Float16* __restrict__ qh,
                                                    const _Float16* __restrict__ wkh,
                                                    float* __restrict__ S) {
  __shared__ __align__(16) char smem[49152];
  const int z = blockIdx.x, i0 = blockIdx.y * 128, b = blockIdx.z;
  const int tid = threadIdx.x, lane = tid & 63, wave = tid >> 6;
  const int wm = wave >> 1, wn = wave & 1, r16 = lane & 15, kg = lane >> 4;
  const int tmin = SEQN - 128 - i0;

  f32x4 acc[4][4];
#pragma unroll
  for (int mf = 0; mf < 4; mf++)
#pragma unroll
    for (int nf = 0; nf < 4; nf++) acc[mf][nf] = (f32x4){0.f, 0.f, 0.f, 0.f};

  ProvRel prov{(const char*)(qh + (size_t)(b * SEQN + i0) * DD),
               (const char*)wkh, tmin + z * 128};
  gemm_core_cnt<16>(prov, smem, acc);

  // scatter-add: band col bc -> j = bc + i' - 127
#pragma unroll
  for (int mf = 0; mf < 4; mf++)
#pragma unroll
    for (int nf = 0; nf < 4; nf++) {
      int bcg = z * 128 + wn * 64 + nf * 16 + r16;
#pragma unroll
      for (int r = 0; r < 4; r++) {
        int ii = wm * 64 + mf * 16 + kg * 4 + r;
        int j = bcg + ii - 127;
        if (bcg <= 2174 && j >= 0 && j < SEQN)
          S[(size_t)(b * SEQN + i0 + ii) * SEQN + j] += acc[mf][nf][r];
      }
    }
}

// -------- softmax over rows of S (in place -> p) + ph = f16(p) sidecar ------
__global__ __launch_bounds__(256) void softmax_rows_k(float* __restrict__ S,
                                                      _Float16* __restrict__ ph) {
  const int wid = threadIdx.x >> 6, lane = threadIdx.x & 63;
  const size_t row = (size_t)blockIdx.x * 4 + wid;
  float* p = S + row * SEQN;
  _Float16* phr = ph + row * SEQN;
  f32x4 x[8];
  float m = -3.4e38f;
#pragma unroll
  for (int c = 0; c < 8; c++) {
    x[c] = *(const f32x4*)(p + c * 256 + lane * 4);
    m = fmaxf(m, fmaxf(fmaxf(x[c][0], x[c][1]), fmaxf(x[c][2], x[c][3])));
  }
#pragma unroll
  for (int off = 32; off > 0; off >>= 1) m = fmaxf(m, __shfl_xor(m, off));
  float s = 0.f;
#pragma unroll
  for (int c = 0; c < 8; c++)
#pragma unroll
    for (int e = 0; e < 4; e++) {
      x[c][e] = __expf(x[c][e] - m);
      s += x[c][e];
    }
#pragma unroll
  for (int off = 32; off > 0; off >>= 1) s += __shfl_xor(s, off);
  float inv = 1.f / s;
#pragma unroll
  for (int c = 0; c < 8; c++) {
    x[c][0] *= inv; x[c][1] *= inv; x[c][2] *= inv; x[c][3] *= inv;
    *(f32x4*)(p + c * 256 + lane * 4) = x[c];
    h16x4 h = {(_Float16)x[c][0], (_Float16)x[c][1], (_Float16)x[c][2], (_Float16)x[c][3]};
    *(h16x4*)(phr + c * 256 + lane * 4) = h;
  }
}

// ------- out = p.v + skew(p).w_v — loop1 A from ph, loop2 range-split -------
// 132 K-steps: t in [0,64) = ph.v ; t in [64,132) = skew(p).w_v (f32 gather,
// predicates only on edge steps t in {64..67, 128..131}).
// 2-phase reg-prefetch, 2x16KB LDS double buffer, 1 barrier/step (r5-proven).
__global__ __launch_bounds__(256) void out_gemm6_k(const _Float16* __restrict__ ph,
                                                   const float* __restrict__ S,
                                                   const _Float16* __restrict__ vT,
                                                   const _Float16* __restrict__ wvT,
                                                   float* __restrict__ outp) {
  __shared__ __align__(16) char smem[32768];
  // XCD-aware decode: 4 d-tiles sharing (i0,b)'s p rows land on one XCD.
  const int bid = blockIdx.x;
  const int xcd = bid & 7, rr = bid >> 3;
  const int x = rr & 3, s8 = rr >> 2;
  const int sidx = xcd + 8 * s8;             // [0,128): (i-tile, b), bijective
  const int d0 = x * 128, i0 = (sidx & 15) * 128, b = sidx >> 4;
  const int tid = threadIdx.x, lane = tid & 63, wave = tid >> 6;
  const int wm = wave >> 1, wn = wave & 1, r16 = lane & 15, kg = lane >> 4;
  const int tmin = SEQN - 128 - i0;

  const _Float16* pb = ph + (size_t)(b * SEQN + i0) * SEQN;  // f16 p (loop 1)
  const float*    pf = S  + (size_t)(b * SEQN + i0) * SEQN;  // f32 p (loop 2 gather)
  const _Float16* vb = vT + (size_t)(b * DD + d0) * SEQN;
  const _Float16* wb = wvT + (size_t)d0 * WPAD + tmin;

  f32x4 acc[4][4];
#pragma unroll
  for (int mf = 0; mf < 4; mf++)
#pragma unroll
    for (int nf = 0; nf < 4; nf++) acc[mf][nf] = (f32x4){0.f, 0.f, 0.f, 0.f};

  h16x4 rav[4], rbv[4];   // staged A/B fragments (f16)

  auto LOADREGS = [&](int t) {
    if (t < 64) {
      const int k0 = t * 32;
#pragma unroll
      for (int rep = 0; rep < 4; rep++) {
        int f = rep * 256 + tid, row = f >> 3, c4 = f & 7;
        rav[rep] = *(const h16x4*)(pb + (size_t)row * SEQN + k0 + c4 * 4);
        rbv[rep] = *(const h16x4*)(vb + (size_t)row * SEQN + k0 + c4 * 4);
      }
    } else {
      const int k0 = (t - 64) * 32;
      const bool clean = (t >= 68) && (t < 128);   // j provably in [1,2047]
#pragma unroll
      for (int rep = 0; rep < 4; rep++) {
        int f = rep * 256 + tid, row = f >> 3, c4 = f & 7;
        int jb = k0 + c4 * 4 + row - 127;
        const float* pr = pf + (size_t)row * SEQN;
        f32x4 v4;
        if (clean) {
          __builtin_memcpy(&v4, pr + jb, 16);      // unpredicated, 4B-aligned
        } else {
#pragma unroll
          for (int e = 0; e < 4; e++) {
            int j = jb + e;
            v4[e] = (j >= 0 && j < SEQN) ? pr[j] : 0.f;
          }
        }
        rav[rep] = h16x4{(_Float16)v4[0], (_Float16)v4[1],
                         (_Float16)v4[2], (_Float16)v4[3]};
        rbv[rep] = *(const h16x4*)(wb + (size_t)row * WPAD + k0 + c4 * 4);
      }
    }
  };
  auto WRITE = [&](char* lb) {
#pragma unroll
    for (int rep = 0; rep < 4; rep++) {
      int f = rep * 256 + tid, row = f >> 3, c4 = f & 7;
      *(h16x4*)(lb + swzw(row, c4)) = rav[rep];
      *(h16x4*)(lb + 8192 + swzw(row, c4)) = rbv[rep];
    }
  };

  LOADREGS(0);
  WRITE(smem);
  LOADREGS(1);                 // tile 1 pending in regs
  __syncthreads();             // tile 0 visible

  for (int t = 0; t < 132; t++) {
    char* lb = smem + (t & 1) * 16384;
    if (t + 1 < 132) WRITE(smem + ((t + 1) & 1) * 16384);   // WAR-safe
    h16x8 af[4], bf[4];
#pragma unroll
    for (int mf = 0; mf < 4; mf++)
      af[mf] = *(const h16x8*)(lb + swzr(wm * 64 + mf * 16 + r16, kg));
#pragma unroll
    for (int nf = 0; nf < 4; nf++)
      bf[nf] = *(const h16x8*)(lb + 8192 + swzr(wn * 64 + nf * 16 + r16, kg));
    if (t + 2 < 132) LOADREGS(t + 2);                        // issue early
#pragma unroll
    for (int mf = 0; mf < 4; mf++)
#pragma unroll
      for (int nf = 0; nf < 4; nf++)
        acc[mf][nf] = __builtin_amdgcn_mfma_f32_16x16x32_f16(af[mf], bf[nf], acc[mf][nf], 0, 0, 0);
    __syncthreads();
  }

#pragma unroll
  for (int mf = 0; mf < 4; mf++)
#pragma unroll
    for (int nf = 0; nf < 4; nf++)
#pragma unroll
      for (int r = 0; r < 4; r++) {
        int ii = wm * 64 + mf * 16 + kg * 4 + r;
        int dd = wn * 64 + nf * 16 + r16;
        outp[(size_t)(b * SEQN + i0 + ii) * DD + d0 + dd] = acc[mf][nf][r];
      }
}

extern "C" void kernel_launch(void* const* d_in, const int* in_sizes, int n_in,
                              void* d_out, int out_size, void* d_ws, size_t ws_size,
                              hipStream_t stream) {
  const float* q  = (const float*)d_in[0];
  const float* k  = (const float*)d_in[1];
  const float* v  = (const float*)d_in[2];
  const float* wk = (const float*)d_in[3];
  const float* wv = (const float*)d_in[4];

  float* outp = (float*)d_out;
  float* S    = outp + (size_t)NB * SEQN * DD;   // p region of d_out doubles as S

  // ws layout (f16 elems): vT | wvT | qh | kh | wkh | ph = 125.8 MB
  // (ws_size >= 201.3 MB proven: rounds 2-4/10 executed a larger layout)
  const size_t nVT = (size_t)NB * DD * SEQN;     // 8388608
  const size_t nWV = (size_t)DD * WPAD;          // 2097152
  const size_t nQH = (size_t)NB * SEQN * DD;     // 8388608
  const size_t nWK = 2097152;                    // 4095*512 rounded up
  _Float16* vT  = (_Float16*)d_ws;
  _Float16* wvT = vT + nVT;
  _Float16* qh  = wvT + nWV;
  _Float16* kh  = qh + nQH;
  _Float16* wkh = kh + nQH;
  _Float16* ph  = wkh + nWK;

  cvt_f16_k<<<dim3(2048), 256, 0, stream>>>(q,  qh,  (long)(nQH / 8));
  cvt_f16_k<<<dim3(2048), 256, 0, stream>>>(k,  kh,  (long)(nQH / 8));
  cvt_f16_k<<<dim3(1024), 256, 0, stream>>>(wk, wkh, (long)((size_t)WROWS * DD / 8));
  transpose_v_k <<<dim3(DD / 32, SEQN / 32, NB), 256, 0, stream>>>(v, vT);
  transpose_wv_k<<<dim3(DD / 32, 128),           256, 0, stream>>>(wv, wvT);

  score_base2_k <<<dim3(SEQN / 128, SEQN / 128, NB), 256, 0, stream>>>(qh, kh, S);
  score_rel2_k  <<<dim3(17, SEQN / 128, NB),         256, 0, stream>>>(qh, wkh, S);
  softmax_rows_k<<<dim3(NB * SEQN / 4),              256, 0, stream>>>(S, ph);
  out_gemm6_k   <<<dim3(512),                        256, 0, stream>>>(ph, S, vT, wvT, outp);
}

// Round 12
// 421.618 us; speedup vs baseline: 1.0308x; 1.0007x over previous
//
#include <hip/hip_runtime.h>

// RelativeAttention B=8, N=2048, D=512, fp32 in, (out[B,N,D], p[B,N,N]) fp32 out.
//
// Round-12: r11 verbatim except ONE mechanism change in out_gemm: the
// per-K-step __syncthreads (which lowers to s_waitcnt vmcnt(0) lgkmcnt(0);
// s_barrier and drains the JUST-ISSUED t+2 prefetch loads -> ~3180 cy/step
// stall, r11 PMC) is replaced by s_waitcnt lgkmcnt(0); s_barrier;
// sched_barrier(0). Reg-staged tiles only need LDS ordering at the barrier;
// the vmem->VGPR deps are compiler-tracked (auto counted vmcnt at the
// ds_write use). Loads now stay in flight across barriers (T4).
// Data path identical to r11 -> absmax must be exactly 0.0859375.

#define SEQN 2048
#define DD   512
#define NB   8
#define WROWS 4095   // 2N-1
#define WPAD  4096   // padded row stride for wvT

typedef float     f32x4 __attribute__((ext_vector_type(4)));
typedef _Float16  h16x4 __attribute__((ext_vector_type(4)));
typedef _Float16  h16x8 __attribute__((ext_vector_type(8)));

__device__ __forceinline__ unsigned swzw(int row, int c4) {
  unsigned b = (unsigned)(row * 64 + c4 * 8);
  return b ^ (((unsigned)row & 6u) << 3);
}
__device__ __forceinline__ unsigned swzr(int row, int kg) {
  unsigned b = (unsigned)(row * 64 + kg * 16);
  return b ^ (((unsigned)row & 6u) << 3);
}

typedef const __attribute__((address_space(1))) unsigned int gu32_t;
typedef __attribute__((address_space(3))) unsigned int lu32_t;
__device__ __forceinline__ void gload_lds16(const void* g, void* l) {
  __builtin_amdgcn_global_load_lds((gu32_t*)g, (lu32_t*)l, 16, 0, 0);
}

// ---------------------------------------------------------------------------
// Counted-vmcnt depth-2 gl_lds core (verified r9): 128x128 tile, 4 waves,
// K-step 32 (64 B/row f16), 3 LDS buffers of 16 KB (A at +0, B at +8192).
// vmcnt(8) = 2 tiles x 4 loads/wave in flight.
// ---------------------------------------------------------------------------
template <class P>
__device__ __forceinline__ void stage_tile(const P& prov, char* smem, int buf,
                                           int t, int wave, int l4, int cp) {
  char* lb = smem + buf * 16384;
#pragma unroll
  for (int h = 0; h < 2; h++) {
    int R = wave * 32 + h * 16;
    int row = R + l4;
    int c = cp ^ ((row >> 1) & 3);
    gload_lds16((const char*)prov.a_src(t, row) + c * 16, lb + R * 64);
    gload_lds16((const char*)prov.b_src(t, row) + c * 16, lb + 8192 + R * 64);
  }
}

template <int NT, class P>
__device__ __forceinline__ void gemm_core_cnt(const P& prov, char* smem, f32x4 (&acc)[4][4]) {
  const int tid = threadIdx.x;
  const int lane = tid & 63, wave = tid >> 6;
  const int l4 = lane >> 2, cp = lane & 3;
  const int wm = wave >> 1, wn = wave & 1;
  const int r16 = lane & 15, kg = lane >> 4;

  stage_tile(prov, smem, 0, 0, wave, l4, cp);
  stage_tile(prov, smem, 1, 1, wave, l4, cp);
  stage_tile(prov, smem, 2, 2, wave, l4, cp);

  int buf = 0;
  for (int t = 0; t < NT; t++) {
    asm volatile("s_waitcnt vmcnt(8)" ::: "memory");
    __builtin_amdgcn_s_barrier();
    char* lb = smem + buf * 16384;
    h16x8 af[4], bf[4];
#pragma unroll
    for (int mf = 0; mf < 4; mf++)
      af[mf] = *(const h16x8*)(lb + swzr(wm * 64 + mf * 16 + r16, kg));
#pragma unroll
    for (int nf = 0; nf < 4; nf++)
      bf[nf] = *(const h16x8*)(lb + 8192 + swzr(wn * 64 + nf * 16 + r16, kg));
#pragma unroll
    for (int mf = 0; mf < 4; mf++)
#pragma unroll
      for (int nf = 0; nf < 4; nf++)
        acc[mf][nf] = __builtin_amdgcn_mfma_f32_16x16x32_f16(af[mf], bf[nf], acc[mf][nf], 0, 0, 0);
    asm volatile("s_waitcnt lgkmcnt(0)" ::: "memory");
    __builtin_amdgcn_s_barrier();
    int nt2 = t + 3; if (nt2 >= NT) nt2 = NT - 1;   // clamped restage keeps vmcnt counting uniform
    stage_tile(prov, smem, buf, nt2, wave, l4, cp);
    buf = (buf == 2) ? 0 : buf + 1;
  }
}

// ---------------- providers -------------------------------------------------
struct ProvQK {   // base scores: A=q_h rows i, B=k_h rows j (stride 1024 B)
  const char *ar, *br;
  __device__ __forceinline__ const void* a_src(int t, int row) const {
    return ar + (size_t)row * 1024 + (size_t)t * 64;
  }
  __device__ __forceinline__ const void* b_src(int t, int row) const {
    return br + (size_t)row * 1024 + (size_t)t * 64;
  }
};
struct ProvRel {  // rel scores: A=q_h, B=wk_h band rows (clamped)
  const char *ar, *wk; int tb;
  __device__ __forceinline__ const void* a_src(int t, int row) const {
    return ar + (size_t)row * 1024 + (size_t)t * 64;
  }
  __device__ __forceinline__ const void* b_src(int t, int row) const {
    int tr = tb + row; if (tr > WROWS - 1) tr = WROWS - 1;
    return wk + (size_t)tr * 1024 + (size_t)t * 64;
  }
};

// ---------------- f32 -> f16 bulk convert -----------------------------------
__global__ __launch_bounds__(256) void cvt_f16_k(const float* __restrict__ in,
                                                 _Float16* __restrict__ out, long n8) {
  for (long i = (long)blockIdx.x * 256 + threadIdx.x; i < n8; i += (long)gridDim.x * 256) {
    f32x4 a = ((const f32x4*)in)[i * 2];
    f32x4 b = ((const f32x4*)in)[i * 2 + 1];
    h16x8 h = {(_Float16)a[0], (_Float16)a[1], (_Float16)a[2], (_Float16)a[3],
               (_Float16)b[0], (_Float16)b[1], (_Float16)b[2], (_Float16)b[3]};
    ((h16x8*)out)[i] = h;
  }
}

// ---------------- transpose v [B,N,D] f32 -> vT [B,D,N] f16 ----------------
__global__ __launch_bounds__(256) void transpose_v_k(const float* __restrict__ v,
                                                     _Float16* __restrict__ vT) {
  __shared__ float tile[32][33];
  const int d0 = blockIdx.x * 32, j0 = blockIdx.y * 32, b = blockIdx.z;
  const int tid = threadIdx.x;
#pragma unroll
  for (int rep = 0; rep < 4; rep++) {
    int idx = rep * 256 + tid;
    int rr = idx >> 5, cc = idx & 31;
    tile[rr][cc] = v[((size_t)(b * SEQN + j0 + rr)) * DD + d0 + cc];
  }
  __syncthreads();
#pragma unroll
  for (int rep = 0; rep < 4; rep++) {
    int idx = rep * 256 + tid;
    int rr = idx >> 5, cc = idx & 31;
    vT[((size_t)(b * DD + d0 + rr)) * SEQN + j0 + cc] = (_Float16)tile[cc][rr];
  }
}

// ------------- transpose w_v [4095,512] f32 -> wvT [512,4096] f16 -----------
__global__ __launch_bounds__(256) void transpose_wv_k(const float* __restrict__ wv,
                                                      _Float16* __restrict__ wvT) {
  __shared__ float tile[32][33];
  const int d0 = blockIdx.x * 32, r0 = blockIdx.y * 32;
  const int tid = threadIdx.x;
#pragma unroll
  for (int rep = 0; rep < 4; rep++) {
    int idx = rep * 256 + tid;
    int rr = idx >> 5, cc = idx & 31;
    float val = 0.f;
    if (r0 + rr < WROWS) val = wv[(size_t)(r0 + rr) * DD + d0 + cc];
    tile[rr][cc] = val;
  }
  __syncthreads();
#pragma unroll
  for (int rep = 0; rep < 4; rep++) {
    int idx = rep * 256 + tid;
    int rr = idx >> 5, cc = idx & 31;
    wvT[(size_t)(d0 + rr) * WPAD + r0 + cc] = (_Float16)tile[cc][rr];
  }
}

// ---------------- score kernels: counted-vmcnt gl_lds core ------------------
__global__ __launch_bounds__(256) void score_base2_k(const _Float16* __restrict__ qh,
                                                     const _Float16* __restrict__ kh,
                                                     float* __restrict__ S) {
  __shared__ __align__(16) char smem[49152];
  const int j0 = blockIdx.x * 128, i0 = blockIdx.y * 128, b = blockIdx.z;
  const int tid = threadIdx.x, lane = tid & 63, wave = tid >> 6;
  const int wm = wave >> 1, wn = wave & 1, r16 = lane & 15, kg = lane >> 4;

  f32x4 acc[4][4];
#pragma unroll
  for (int mf = 0; mf < 4; mf++)
#pragma unroll
    for (int nf = 0; nf < 4; nf++) acc[mf][nf] = (f32x4){0.f, 0.f, 0.f, 0.f};

  ProvQK prov{(const char*)(qh + (size_t)(b * SEQN + i0) * DD),
              (const char*)(kh + (size_t)(b * SEQN + j0) * DD)};
  gemm_core_cnt<16>(prov, smem, acc);

#pragma unroll
  for (int mf = 0; mf < 4; mf++)
#pragma unroll
    for (int nf = 0; nf < 4; nf++)
#pragma unroll
      for (int r = 0; r < 4; r++) {
        int ii = wm * 64 + mf * 16 + kg * 4 + r;
        int jj = wn * 64 + nf * 16 + r16;
        S[(size_t)(b * SEQN + i0 + ii) * SEQN + j0 + jj] = acc[mf][nf][r];
      }
}

__global__ __launch_bounds__(256) void score_rel2_k(const _Float16* __restrict__ qh,
                                                    const _Float16* __restrict__ wkh,
                                                    float* __restrict__ S) {
  __shared__ __align__(16) char smem[49152];
  const int z = blockIdx.x, i0 = blockIdx.y * 128, b = blockIdx.z;
  const int tid = threadIdx.x, lane = tid & 63, wave = tid >> 6;
  const int wm = wave >> 1, wn = wave & 1, r16 = lane & 15, kg = lane >> 4;
  const int tmin = SEQN - 128 - i0;

  f32x4 acc[4][4];
#pragma unroll
  for (int mf = 0; mf < 4; mf++)
#pragma unroll
    for (int nf = 0; nf < 4; nf++) acc[mf][nf] = (f32x4){0.f, 0.f, 0.f, 0.f};

  ProvRel prov{(const char*)(qh + (size_t)(b * SEQN + i0) * DD),
               (const char*)wkh, tmin + z * 128};
  gemm_core_cnt<16>(prov, smem, acc);

  // scatter-add: band col bc -> j = bc + i' - 127
#pragma unroll
  for (int mf = 0; mf < 4; mf++)
#pragma unroll
    for (int nf = 0; nf < 4; nf++) {
      int bcg = z * 128 + wn * 64 + nf * 16 + r16;
#pragma unroll
      for (int r = 0; r < 4; r++) {
        int ii = wm * 64 + mf * 16 + kg * 4 + r;
        int j = bcg + ii - 127;
        if (bcg <= 2174 && j >= 0 && j < SEQN)
          S[(size_t)(b * SEQN + i0 + ii) * SEQN + j] += acc[mf][nf][r];
      }
    }
}

// -------- softmax over rows of S (in place -> p) + ph = f16(p) sidecar ------
__global__ __launch_bounds__(256) void softmax_rows_k(float* __restrict__ S,
                                                      _Float16* __restrict__ ph) {
  const int wid = threadIdx.x >> 6, lane = threadIdx.x & 63;
  const size_t row = (size_t)blockIdx.x * 4 + wid;
  float* p = S + row * SEQN;
  _Float16* phr = ph + row * SEQN;
  f32x4 x[8];
  float m = -3.4e38f;
#pragma unroll
  for (int c = 0; c < 8; c++) {
    x[c] = *(const f32x4*)(p + c * 256 + lane * 4);
    m = fmaxf(m, fmaxf(fmaxf(x[c][0], x[c][1]), fmaxf(x[c][2], x[c][3])));
  }
#pragma unroll
  for (int off = 32; off > 0; off >>= 1) m = fmaxf(m, __shfl_xor(m, off));
  float s = 0.f;
#pragma unroll
  for (int c = 0; c < 8; c++)
#pragma unroll
    for (int e = 0; e < 4; e++) {
      x[c][e] = __expf(x[c][e] - m);
      s += x[c][e];
    }
#pragma unroll
  for (int off = 32; off > 0; off >>= 1) s += __shfl_xor(s, off);
  float inv = 1.f / s;
#pragma unroll
  for (int c = 0; c < 8; c++) {
    x[c][0] *= inv; x[c][1] *= inv; x[c][2] *= inv; x[c][3] *= inv;
    *(f32x4*)(p + c * 256 + lane * 4) = x[c];
    h16x4 h = {(_Float16)x[c][0], (_Float16)x[c][1], (_Float16)x[c][2], (_Float16)x[c][3]};
    *(h16x4*)(phr + c * 256 + lane * 4) = h;
  }
}

// ------- out = p.v + skew(p).w_v — r11 structure, raw-barrier sync ----------
// 132 K-steps: t in [0,64) = ph.v ; t in [64,132) = skew(p).w_v (f32 gather,
// predicates only on edge steps). Per step: lgkmcnt(0)+s_barrier only —
// prefetch loads stay in flight across the barrier (compiler inserts the
// counted vmcnt before the ds_write that consumes the loaded registers).
__global__ __launch_bounds__(256) void out_gemm7_k(const _Float16* __restrict__ ph,
                                                   const float* __restrict__ S,
                                                   const _Float16* __restrict__ vT,
                                                   const _Float16* __restrict__ wvT,
                                                   float* __restrict__ outp) {
  __shared__ __align__(16) char smem[32768];
  // XCD-aware decode: 4 d-tiles sharing (i0,b)'s p rows land on one XCD.
  const int bid = blockIdx.x;
  const int xcd = bid & 7, rr = bid >> 3;
  const int x = rr & 3, s8 = rr >> 2;
  const int sidx = xcd + 8 * s8;             // [0,128): (i-tile, b), bijective
  const int d0 = x * 128, i0 = (sidx & 15) * 128, b = sidx >> 4;
  const int tid = threadIdx.x, lane = tid & 63, wave = tid >> 6;
  const int wm = wave >> 1, wn = wave & 1, r16 = lane & 15, kg = lane >> 4;
  const int tmin = SEQN - 128 - i0;

  const _Float16* pb = ph + (size_t)(b * SEQN + i0) * SEQN;  // f16 p (loop 1)
  const float*    pf = S  + (size_t)(b * SEQN + i0) * SEQN;  // f32 p (loop 2 gather)
  const _Float16* vb = vT + (size_t)(b * DD + d0) * SEQN;
  const _Float16* wb = wvT + (size_t)d0 * WPAD + tmin;

  f32x4 acc[4][4];
#pragma unroll
  for (int mf = 0; mf < 4; mf++)
#pragma unroll
    for (int nf = 0; nf < 4; nf++) acc[mf][nf] = (f32x4){0.f, 0.f, 0.f, 0.f};

  h16x4 rav[4], rbv[4];   // staged A/B fragments (f16)

  auto LOADREGS = [&](int t) {
    if (t < 64) {
      const int k0 = t * 32;
#pragma unroll
      for (int rep = 0; rep < 4; rep++) {
        int f = rep * 256 + tid, row = f >> 3, c4 = f & 7;
        rav[rep] = *(const h16x4*)(pb + (size_t)row * SEQN + k0 + c4 * 4);
        rbv[rep] = *(const h16x4*)(vb + (size_t)row * SEQN + k0 + c4 * 4);
      }
    } else {
      const int k0 = (t - 64) * 32;
      const bool clean = (t >= 68) && (t < 128);   // j provably in [1,2047]
#pragma unroll
      for (int rep = 0; rep < 4; rep++) {
        int f = rep * 256 + tid, row = f >> 3, c4 = f & 7;
        int jb = k0 + c4 * 4 + row - 127;
        const float* pr = pf + (size_t)row * SEQN;
        f32x4 v4;
        if (clean) {
          __builtin_memcpy(&v4, pr + jb, 16);      // unpredicated, 4B-aligned
        } else {
#pragma unroll
          for (int e = 0; e < 4; e++) {
            int j = jb + e;
            v4[e] = (j >= 0 && j < SEQN) ? pr[j] : 0.f;
          }
        }
        rav[rep] = h16x4{(_Float16)v4[0], (_Float16)v4[1],
                         (_Float16)v4[2], (_Float16)v4[3]};
        rbv[rep] = *(const h16x4*)(wb + (size_t)row * WPAD + k0 + c4 * 4);
      }
    }
  };
  auto WRITE = [&](char* lb) {
#pragma unroll
    for (int rep = 0; rep < 4; rep++) {
      int f = rep * 256 + tid, row = f >> 3, c4 = f & 7;
      *(h16x4*)(lb + swzw(row, c4)) = rav[rep];
      *(h16x4*)(lb + 8192 + swzw(row, c4)) = rbv[rep];
    }
  };

  LOADREGS(0);
  WRITE(smem);
  LOADREGS(1);                 // tile 1 pending in regs
  asm volatile("s_waitcnt lgkmcnt(0)" ::: "memory");
  __builtin_amdgcn_s_barrier();          // tile 0 visible; loads stay in flight
  __builtin_amdgcn_sched_barrier(0);

  for (int t = 0; t < 132; t++) {
    char* lb = smem + (t & 1) * 16384;
    if (t + 1 < 132) WRITE(smem + ((t + 1) & 1) * 16384);   // WAR-safe
    h16x8 af[4], bf[4];
#pragma unroll
    for (int mf = 0; mf < 4; mf++)
      af[mf] = *(const h16x8*)(lb + swzr(wm * 64 + mf * 16 + r16, kg));
#pragma unroll
    for (int nf = 0; nf < 4; nf++)
      bf[nf] = *(const h16x8*)(lb + 8192 + swzr(wn * 64 + nf * 16 + r16, kg));
    if (t + 2 < 132) LOADREGS(t + 2);                        // issue early
#pragma unroll
    for (int mf = 0; mf < 4; mf++)
#pragma unroll
      for (int nf = 0; nf < 4; nf++)
        acc[mf][nf] = __builtin_amdgcn_mfma_f32_16x16x32_f16(af[mf], bf[nf], acc[mf][nf], 0, 0, 0);
    asm volatile("s_waitcnt lgkmcnt(0)" ::: "memory");   // ds ops done; NO vmem drain
    __builtin_amdgcn_s_barrier();
    __builtin_amdgcn_sched_barrier(0);
  }

#pragma unroll
  for (int mf = 0; mf < 4; mf++)
#pragma unroll
    for (int nf = 0; nf < 4; nf++)
#pragma unroll
      for (int r = 0; r < 4; r++) {
        int ii = wm * 64 + mf * 16 + kg * 4 + r;
        int dd = wn * 64 + nf * 16 + r16;
        outp[(size_t)(b * SEQN + i0 + ii) * DD + d0 + dd] = acc[mf][nf][r];
      }
}

extern "C" void kernel_launch(void* const* d_in, const int* in_sizes, int n_in,
                              void* d_out, int out_size, void* d_ws, size_t ws_size,
                              hipStream_t stream) {
  const float* q  = (const float*)d_in[0];
  const float* k  = (const float*)d_in[1];
  const float* v  = (const float*)d_in[2];
  const float* wk = (const float*)d_in[3];
  const float* wv = (const float*)d_in[4];

  float* outp = (float*)d_out;
  float* S    = outp + (size_t)NB * SEQN * DD;   // p region of d_out doubles as S

  // ws layout (f16 elems): vT | wvT | qh | kh | wkh | ph = 125.8 MB
  const size_t nVT = (size_t)NB * DD * SEQN;     // 8388608
  const size_t nWV = (size_t)DD * WPAD;          // 2097152
  const size_t nQH = (size_t)NB * SEQN * DD;     // 8388608
  const size_t nWK = 2097152;                    // 4095*512 rounded up
  _Float16* vT  = (_Float16*)d_ws;
  _Float16* wvT = vT + nVT;
  _Float16* qh  = wvT + nWV;
  _Float16* kh  = qh + nQH;
  _Float16* wkh = kh + nQH;
  _Float16* ph  = wkh + nWK;

  cvt_f16_k<<<dim3(2048), 256, 0, stream>>>(q,  qh,  (long)(nQH / 8));
  cvt_f16_k<<<dim3(2048), 256, 0, stream>>>(k,  kh,  (long)(nQH / 8));
  cvt_f16_k<<<dim3(1024), 256, 0, stream>>>(wk, wkh, (long)((size_t)WROWS * DD / 8));
  transpose_v_k <<<dim3(DD / 32, SEQN / 32, NB), 256, 0, stream>>>(v, vT);
  transpose_wv_k<<<dim3(DD / 32, 128),           256, 0, stream>>>(wv, wvT);

  score_base2_k <<<dim3(SEQN / 128, SEQN / 128, NB), 256, 0, stream>>>(qh, kh, S);
  score_rel2_k  <<<dim3(17, SEQN / 128, NB),         256, 0, stream>>>(qh, wkh, S);
  softmax_rows_k<<<dim3(NB * SEQN / 4),              256, 0, stream>>>(S, ph);
  out_gemm7_k   <<<dim3(512),                        256, 0, stream>>>(ph, S, vT, wvT, outp);
}

// Round 13
// 419.022 us; speedup vs baseline: 1.0372x; 1.0062x over previous
//
#include <hip/hip_runtime.h>

// RelativeAttention B=8, N=2048, D=512, fp32 in, (out[B,N,D], p[B,N,N]) fp32 out.
//
// Round-13: r12 verbatim except out_gemm gains DEPTH-2 register prefetch:
// two named tile-sets PA/PB (loop unrolled x2 so all set selection is
// compile-time -> no scratch, rule #20); tile t+3 is loaded into the set
// just flushed to LDS at step t, giving a 2-step issue->consume gap
// (~2600 cy) that covers HBM latency (~900 cy). r11/r12 exposed ~500+ cy
// per step at the first ds_write (depth-1 gap too short) -> 3180 cy/step.
// Data path bit-identical -> absmax must be exactly 0.0859375.

#define SEQN 2048
#define DD   512
#define NB   8
#define WROWS 4095   // 2N-1
#define WPAD  4096   // padded row stride for wvT

typedef float     f32x4 __attribute__((ext_vector_type(4)));
typedef _Float16  h16x4 __attribute__((ext_vector_type(4)));
typedef _Float16  h16x8 __attribute__((ext_vector_type(8)));

__device__ __forceinline__ unsigned swzw(int row, int c4) {
  unsigned b = (unsigned)(row * 64 + c4 * 8);
  return b ^ (((unsigned)row & 6u) << 3);
}
__device__ __forceinline__ unsigned swzr(int row, int kg) {
  unsigned b = (unsigned)(row * 64 + kg * 16);
  return b ^ (((unsigned)row & 6u) << 3);
}

typedef const __attribute__((address_space(1))) unsigned int gu32_t;
typedef __attribute__((address_space(3))) unsigned int lu32_t;
__device__ __forceinline__ void gload_lds16(const void* g, void* l) {
  __builtin_amdgcn_global_load_lds((gu32_t*)g, (lu32_t*)l, 16, 0, 0);
}

// ---------------------------------------------------------------------------
// Counted-vmcnt depth-2 gl_lds core (verified r9) — scores only.
// ---------------------------------------------------------------------------
template <class P>
__device__ __forceinline__ void stage_tile(const P& prov, char* smem, int buf,
                                           int t, int wave, int l4, int cp) {
  char* lb = smem + buf * 16384;
#pragma unroll
  for (int h = 0; h < 2; h++) {
    int R = wave * 32 + h * 16;
    int row = R + l4;
    int c = cp ^ ((row >> 1) & 3);
    gload_lds16((const char*)prov.a_src(t, row) + c * 16, lb + R * 64);
    gload_lds16((const char*)prov.b_src(t, row) + c * 16, lb + 8192 + R * 64);
  }
}

template <int NT, class P>
__device__ __forceinline__ void gemm_core_cnt(const P& prov, char* smem, f32x4 (&acc)[4][4]) {
  const int tid = threadIdx.x;
  const int lane = tid & 63, wave = tid >> 6;
  const int l4 = lane >> 2, cp = lane & 3;
  const int wm = wave >> 1, wn = wave & 1;
  const int r16 = lane & 15, kg = lane >> 4;

  stage_tile(prov, smem, 0, 0, wave, l4, cp);
  stage_tile(prov, smem, 1, 1, wave, l4, cp);
  stage_tile(prov, smem, 2, 2, wave, l4, cp);

  int buf = 0;
  for (int t = 0; t < NT; t++) {
    asm volatile("s_waitcnt vmcnt(8)" ::: "memory");
    __builtin_amdgcn_s_barrier();
    char* lb = smem + buf * 16384;
    h16x8 af[4], bf[4];
#pragma unroll
    for (int mf = 0; mf < 4; mf++)
      af[mf] = *(const h16x8*)(lb + swzr(wm * 64 + mf * 16 + r16, kg));
#pragma unroll
    for (int nf = 0; nf < 4; nf++)
      bf[nf] = *(const h16x8*)(lb + 8192 + swzr(wn * 64 + nf * 16 + r16, kg));
#pragma unroll
    for (int mf = 0; mf < 4; mf++)
#pragma unroll
      for (int nf = 0; nf < 4; nf++)
        acc[mf][nf] = __builtin_amdgcn_mfma_f32_16x16x32_f16(af[mf], bf[nf], acc[mf][nf], 0, 0, 0);
    asm volatile("s_waitcnt lgkmcnt(0)" ::: "memory");
    __builtin_amdgcn_s_barrier();
    int nt2 = t + 3; if (nt2 >= NT) nt2 = NT - 1;   // clamped restage keeps vmcnt counting uniform
    stage_tile(prov, smem, buf, nt2, wave, l4, cp);
    buf = (buf == 2) ? 0 : buf + 1;
  }
}

// ---------------- providers -------------------------------------------------
struct ProvQK {
  const char *ar, *br;
  __device__ __forceinline__ const void* a_src(int t, int row) const {
    return ar + (size_t)row * 1024 + (size_t)t * 64;
  }
  __device__ __forceinline__ const void* b_src(int t, int row) const {
    return br + (size_t)row * 1024 + (size_t)t * 64;
  }
};
struct ProvRel {
  const char *ar, *wk; int tb;
  __device__ __forceinline__ const void* a_src(int t, int row) const {
    return ar + (size_t)row * 1024 + (size_t)t * 64;
  }
  __device__ __forceinline__ const void* b_src(int t, int row) const {
    int tr = tb + row; if (tr > WROWS - 1) tr = WROWS - 1;
    return wk + (size_t)tr * 1024 + (size_t)t * 64;
  }
};

// ---------------- f32 -> f16 bulk convert -----------------------------------
__global__ __launch_bounds__(256) void cvt_f16_k(const float* __restrict__ in,
                                                 _Float16* __restrict__ out, long n8) {
  for (long i = (long)blockIdx.x * 256 + threadIdx.x; i < n8; i += (long)gridDim.x * 256) {
    f32x4 a = ((const f32x4*)in)[i * 2];
    f32x4 b = ((const f32x4*)in)[i * 2 + 1];
    h16x8 h = {(_Float16)a[0], (_Float16)a[1], (_Float16)a[2], (_Float16)a[3],
               (_Float16)b[0], (_Float16)b[1], (_Float16)b[2], (_Float16)b[3]};
    ((h16x8*)out)[i] = h;
  }
}

// ---------------- transpose v [B,N,D] f32 -> vT [B,D,N] f16 ----------------
__global__ __launch_bounds__(256) void transpose_v_k(const float* __restrict__ v,
                                                     _Float16* __restrict__ vT) {
  __shared__ float tile[32][33];
  const int d0 = blockIdx.x * 32, j0 = blockIdx.y * 32, b = blockIdx.z;
  const int tid = threadIdx.x;
#pragma unroll
  for (int rep = 0; rep < 4; rep++) {
    int idx = rep * 256 + tid;
    int rr = idx >> 5, cc = idx & 31;
    tile[rr][cc] = v[((size_t)(b * SEQN + j0 + rr)) * DD + d0 + cc];
  }
  __syncthreads();
#pragma unroll
  for (int rep = 0; rep < 4; rep++) {
    int idx = rep * 256 + tid;
    int rr = idx >> 5, cc = idx & 31;
    vT[((size_t)(b * DD + d0 + rr)) * SEQN + j0 + cc] = (_Float16)tile[cc][rr];
  }
}

// ------------- transpose w_v [4095,512] f32 -> wvT [512,4096] f16 -----------
__global__ __launch_bounds__(256) void transpose_wv_k(const float* __restrict__ wv,
                                                      _Float16* __restrict__ wvT) {
  __shared__ float tile[32][33];
  const int d0 = blockIdx.x * 32, r0 = blockIdx.y * 32;
  const int tid = threadIdx.x;
#pragma unroll
  for (int rep = 0; rep < 4; rep++) {
    int idx = rep * 256 + tid;
    int rr = idx >> 5, cc = idx & 31;
    float val = 0.f;
    if (r0 + rr < WROWS) val = wv[(size_t)(r0 + rr) * DD + d0 + cc];
    tile[rr][cc] = val;
  }
  __syncthreads();
#pragma unroll
  for (int rep = 0; rep < 4; rep++) {
    int idx = rep * 256 + tid;
    int rr = idx >> 5, cc = idx & 31;
    wvT[(size_t)(d0 + rr) * WPAD + r0 + cc] = (_Float16)tile[cc][rr];
  }
}

// ---------------- score kernels: counted-vmcnt gl_lds core ------------------
__global__ __launch_bounds__(256) void score_base2_k(const _Float16* __restrict__ qh,
                                                     const _Float16* __restrict__ kh,
                                                     float* __restrict__ S) {
  __shared__ __align__(16) char smem[49152];
  const int j0 = blockIdx.x * 128, i0 = blockIdx.y * 128, b = blockIdx.z;
  const int tid = threadIdx.x, lane = tid & 63, wave = tid >> 6;
  const int wm = wave >> 1, wn = wave & 1, r16 = lane & 15, kg = lane >> 4;

  f32x4 acc[4][4];
#pragma unroll
  for (int mf = 0; mf < 4; mf++)
#pragma unroll
    for (int nf = 0; nf < 4; nf++) acc[mf][nf] = (f32x4){0.f, 0.f, 0.f, 0.f};

  ProvQK prov{(const char*)(qh + (size_t)(b * SEQN + i0) * DD),
              (const char*)(kh + (size_t)(b * SEQN + j0) * DD)};
  gemm_core_cnt<16>(prov, smem, acc);

#pragma unroll
  for (int mf = 0; mf < 4; mf++)
#pragma unroll
    for (int nf = 0; nf < 4; nf++)
#pragma unroll
      for (int r = 0; r < 4; r++) {
        int ii = wm * 64 + mf * 16 + kg * 4 + r;
        int jj = wn * 64 + nf * 16 + r16;
        S[(size_t)(b * SEQN + i0 + ii) * SEQN + j0 + jj] = acc[mf][nf][r];
      }
}

__global__ __launch_bounds__(256) void score_rel2_k(const _Float16* __restrict__ qh,
                                                    const _Float16* __restrict__ wkh,
                                                    float* __restrict__ S) {
  __shared__ __align__(16) char smem[49152];
  const int z = blockIdx.x, i0 = blockIdx.y * 128, b = blockIdx.z;
  const int tid = threadIdx.x, lane = tid & 63, wave = tid >> 6;
  const int wm = wave >> 1, wn = wave & 1, r16 = lane & 15, kg = lane >> 4;
  const int tmin = SEQN - 128 - i0;

  f32x4 acc[4][4];
#pragma unroll
  for (int mf = 0; mf < 4; mf++)
#pragma unroll
    for (int nf = 0; nf < 4; nf++) acc[mf][nf] = (f32x4){0.f, 0.f, 0.f, 0.f};

  ProvRel prov{(const char*)(qh + (size_t)(b * SEQN + i0) * DD),
               (const char*)wkh, tmin + z * 128};
  gemm_core_cnt<16>(prov, smem, acc);

  // scatter-add: band col bc -> j = bc + i' - 127
#pragma unroll
  for (int mf = 0; mf < 4; mf++)
#pragma unroll
    for (int nf = 0; nf < 4; nf++) {
      int bcg = z * 128 + wn * 64 + nf * 16 + r16;
#pragma unroll
      for (int r = 0; r < 4; r++) {
        int ii = wm * 64 + mf * 16 + kg * 4 + r;
        int j = bcg + ii - 127;
        if (bcg <= 2174 && j >= 0 && j < SEQN)
          S[(size_t)(b * SEQN + i0 + ii) * SEQN + j] += acc[mf][nf][r];
      }
    }
}

// -------- softmax over rows of S (in place -> p) + ph = f16(p) sidecar ------
__global__ __launch_bounds__(256) void softmax_rows_k(float* __restrict__ S,
                                                      _Float16* __restrict__ ph) {
  const int wid = threadIdx.x >> 6, lane = threadIdx.x & 63;
  const size_t row = (size_t)blockIdx.x * 4 + wid;
  float* p = S + row * SEQN;
  _Float16* phr = ph + row * SEQN;
  f32x4 x[8];
  float m = -3.4e38f;
#pragma unroll
  for (int c = 0; c < 8; c++) {
    x[c] = *(const f32x4*)(p + c * 256 + lane * 4);
    m = fmaxf(m, fmaxf(fmaxf(x[c][0], x[c][1]), fmaxf(x[c][2], x[c][3])));
  }
#pragma unroll
  for (int off = 32; off > 0; off >>= 1) m = fmaxf(m, __shfl_xor(m, off));
  float s = 0.f;
#pragma unroll
  for (int c = 0; c < 8; c++)
#pragma unroll
    for (int e = 0; e < 4; e++) {
      x[c][e] = __expf(x[c][e] - m);
      s += x[c][e];
    }
#pragma unroll
  for (int off = 32; off > 0; off >>= 1) s += __shfl_xor(s, off);
  float inv = 1.f / s;
#pragma unroll
  for (int c = 0; c < 8; c++) {
    x[c][0] *= inv; x[c][1] *= inv; x[c][2] *= inv; x[c][3] *= inv;
    *(f32x4*)(p + c * 256 + lane * 4) = x[c];
    h16x4 h = {(_Float16)x[c][0], (_Float16)x[c][1], (_Float16)x[c][2], (_Float16)x[c][3]};
    *(h16x4*)(phr + c * 256 + lane * 4) = h;
  }
}

// ------- out = p.v + skew(p).w_v — depth-2 register prefetch ----------------
// 132 K-steps: t in [0,64) = ph.v ; t in [64,132) = skew(p).w_v (f32 gather,
// predicates only on edge steps). Two named reg tile-sets PA/PB; loop
// unrolled x2 so set selection is compile-time. At step t: WRITE tile t+1
// from P[(t+1)&1], then LOAD tile t+3 into the SAME set (safe: ds_write
// reads regs at issue). Issue->consume gap = 2 steps.
struct RegTile { h16x4 a[4]; h16x4 b[4]; };

__global__ __launch_bounds__(256) void out_gemm8_k(const _Float16* __restrict__ ph,
                                                   const float* __restrict__ S,
                                                   const _Float16* __restrict__ vT,
                                                   const _Float16* __restrict__ wvT,
                                                   float* __restrict__ outp) {
  __shared__ __align__(16) char smem[32768];
  const int bid = blockIdx.x;
  const int xcd = bid & 7, rr = bid >> 3;
  const int x = rr & 3, s8 = rr >> 2;
  const int sidx = xcd + 8 * s8;             // [0,128): (i-tile, b), bijective
  const int d0 = x * 128, i0 = (sidx & 15) * 128, b = sidx >> 4;
  const int tid = threadIdx.x, lane = tid & 63, wave = tid >> 6;
  const int wm = wave >> 1, wn = wave & 1, r16 = lane & 15, kg = lane >> 4;
  const int tmin = SEQN - 128 - i0;

  const _Float16* pb = ph + (size_t)(b * SEQN + i0) * SEQN;  // f16 p (loop 1)
  const float*    pf = S  + (size_t)(b * SEQN + i0) * SEQN;  // f32 p (loop 2 gather)
  const _Float16* vb = vT + (size_t)(b * DD + d0) * SEQN;
  const _Float16* wb = wvT + (size_t)d0 * WPAD + tmin;

  f32x4 acc[4][4];
#pragma unroll
  for (int mf = 0; mf < 4; mf++)
#pragma unroll
    for (int nf = 0; nf < 4; nf++) acc[mf][nf] = (f32x4){0.f, 0.f, 0.f, 0.f};

  RegTile PA, PB;

  auto LOADREGS = [&](int t, RegTile& R) {
    if (t < 64) {
      const int k0 = t * 32;
#pragma unroll
      for (int rep = 0; rep < 4; rep++) {
        int f = rep * 256 + tid, row = f >> 3, c4 = f & 7;
        R.a[rep] = *(const h16x4*)(pb + (size_t)row * SEQN + k0 + c4 * 4);
        R.b[rep] = *(const h16x4*)(vb + (size_t)row * SEQN + k0 + c4 * 4);
      }
    } else {
      const int k0 = (t - 64) * 32;
      const bool clean = (t >= 68) && (t < 128);   // j provably in [1,2047]
#pragma unroll
      for (int rep = 0; rep < 4; rep++) {
        int f = rep * 256 + tid, row = f >> 3, c4 = f & 7;
        int jb = k0 + c4 * 4 + row - 127;
        const float* pr = pf + (size_t)row * SEQN;
        f32x4 v4;
        if (clean) {
          __builtin_memcpy(&v4, pr + jb, 16);      // unpredicated, 4B-aligned
        } else {
#pragma unroll
          for (int e = 0; e < 4; e++) {
            int j = jb + e;
            v4[e] = (j >= 0 && j < SEQN) ? pr[j] : 0.f;
          }
        }
        R.a[rep] = h16x4{(_Float16)v4[0], (_Float16)v4[1],
                         (_Float16)v4[2], (_Float16)v4[3]};
        R.b[rep] = *(const h16x4*)(wb + (size_t)row * WPAD + k0 + c4 * 4);
      }
    }
  };
  auto WRITE = [&](char* lb, const RegTile& R) {
#pragma unroll
    for (int rep = 0; rep < 4; rep++) {
      int f = rep * 256 + tid, row = f >> 3, c4 = f & 7;
      *(h16x4*)(lb + swzw(row, c4)) = R.a[rep];
      *(h16x4*)(lb + 8192 + swzw(row, c4)) = R.b[rep];
    }
  };
  auto COMPUTE = [&](const char* lb) {
    h16x8 af[4], bf[4];
#pragma unroll
    for (int mf = 0; mf < 4; mf++)
      af[mf] = *(const h16x8*)(lb + swzr(wm * 64 + mf * 16 + r16, kg));
#pragma unroll
    for (int nf = 0; nf < 4; nf++)
      bf[nf] = *(const h16x8*)(lb + 8192 + swzr(wn * 64 + nf * 16 + r16, kg));
#pragma unroll
    for (int mf = 0; mf < 4; mf++)
#pragma unroll
      for (int nf = 0; nf < 4; nf++)
        acc[mf][nf] = __builtin_amdgcn_mfma_f32_16x16x32_f16(af[mf], bf[nf], acc[mf][nf], 0, 0, 0);
  };
  auto SYNC = [&]() {
    asm volatile("s_waitcnt lgkmcnt(0)" ::: "memory");
    __builtin_amdgcn_s_barrier();
    __builtin_amdgcn_sched_barrier(0);
  };

  // prologue: buf0 = tile0; PB = tile1; PA = tile2
  LOADREGS(0, PA);
  WRITE(smem, PA);
  LOADREGS(1, PB);
  LOADREGS(2, PA);
  SYNC();

  for (int t2 = 0; t2 < 132; t2 += 2) {
    // even step t2: read buf0, write buf1 from PB (tile t2+1), load t2+3 -> PB
    WRITE(smem + 16384, PB);
    {
      // split: issue ds_reads inside COMPUTE after write
    }
    COMPUTE(smem);
    if (t2 + 3 < 132) LOADREGS(t2 + 3, PB);
    SYNC();
    // odd step t2+1: read buf1, write buf0 from PA (tile t2+2), load t2+4 -> PA
    if (t2 + 2 < 132) WRITE(smem, PA);
    COMPUTE(smem + 16384);
    if (t2 + 4 < 132) LOADREGS(t2 + 4, PA);
    SYNC();
  }

#pragma unroll
  for (int mf = 0; mf < 4; mf++)
#pragma unroll
    for (int nf = 0; nf < 4; nf++)
#pragma unroll
      for (int r = 0; r < 4; r++) {
        int ii = wm * 64 + mf * 16 + kg * 4 + r;
        int dd = wn * 64 + nf * 16 + r16;
        outp[(size_t)(b * SEQN + i0 + ii) * DD + d0 + dd] = acc[mf][nf][r];
      }
}

extern "C" void kernel_launch(void* const* d_in, const int* in_sizes, int n_in,
                              void* d_out, int out_size, void* d_ws, size_t ws_size,
                              hipStream_t stream) {
  const float* q  = (const float*)d_in[0];
  const float* k  = (const float*)d_in[1];
  const float* v  = (const float*)d_in[2];
  const float* wk = (const float*)d_in[3];
  const float* wv = (const float*)d_in[4];

  float* outp = (float*)d_out;
  float* S    = outp + (size_t)NB * SEQN * DD;   // p region of d_out doubles as S

  // ws layout (f16 elems): vT | wvT | qh | kh | wkh | ph = 125.8 MB
  const size_t nVT = (size_t)NB * DD * SEQN;     // 8388608
  const size_t nWV = (size_t)DD * WPAD;          // 2097152
  const size_t nQH = (size_t)NB * SEQN * DD;     // 8388608
  const size_t nWK = 2097152;                    // 4095*512 rounded up
  _Float16* vT  = (_Float16*)d_ws;
  _Float16* wvT = vT + nVT;
  _Float16* qh  = wvT + nWV;
  _Float16* kh  = qh + nQH;
  _Float16* wkh = kh + nQH;
  _Float16* ph  = wkh + nWK;

  cvt_f16_k<<<dim3(2048), 256, 0, stream>>>(q,  qh,  (long)(nQH / 8));
  cvt_f16_k<<<dim3(2048), 256, 0, stream>>>(k,  kh,  (long)(nQH / 8));
  cvt_f16_k<<<dim3(1024), 256, 0, stream>>>(wk, wkh, (long)((size_t)WROWS * DD / 8));
  transpose_v_k <<<dim3(DD / 32, SEQN / 32, NB), 256, 0, stream>>>(v, vT);
  transpose_wv_k<<<dim3(DD / 32, 128),           256, 0, stream>>>(wv, wvT);

  score_base2_k <<<dim3(SEQN / 128, SEQN / 128, NB), 256, 0, stream>>>(qh, kh, S);
  score_rel2_k  <<<dim3(17, SEQN / 128, NB),         256, 0, stream>>>(qh, wkh, S);
  softmax_rows_k<<<dim3(NB * SEQN / 4),              256, 0, stream>>>(S, ph);
  out_gemm8_k   <<<dim3(512),                        256, 0, stream>>>(ph, S, vT, wvT, outp);
}

// Round 14
// 415.520 us; speedup vs baseline: 1.0459x; 1.0084x over previous
//
#include <hip/hip_runtime.h>

// RelativeAttention B=8, N=2048, D=512, fp32 in, (out[B,N,D], p[B,N,N]) fp32 out.
//
// Round-14: assembly of the measured-best verified pieces (no new mechanisms):
//   - scores: counted-vmcnt depth-2 gl_lds core   (r9: -13us vs drain core)
//   - softmax: lean, no ph sidecar                (r9: sidecar +12us, no payoff)
//   - out: r8's out_gemm3 verbatim                (169us best; r9/r11/r13 >= 172)
// Rationale: r11-r13 pipeline variants all null -> the 128^2/4-wave structure
// is at its skinny-shape ceiling (m102: even the reference structure gives
// ~320TF at N=2048); no PMC pipe >25% so no targeted lever remains at this
// structure. absmax must be exactly 0.0859375 (all pieces bit-verified).

#define SEQN 2048
#define DD   512
#define NB   8
#define WROWS 4095   // 2N-1
#define WPAD  4096   // padded row stride for wvT

typedef float     f32x4 __attribute__((ext_vector_type(4)));
typedef _Float16  h16x4 __attribute__((ext_vector_type(4)));
typedef _Float16  h16x8 __attribute__((ext_vector_type(8)));

__device__ __forceinline__ unsigned swzw(int row, int c4) {
  unsigned b = (unsigned)(row * 64 + c4 * 8);
  return b ^ (((unsigned)row & 6u) << 3);
}
__device__ __forceinline__ unsigned swzr(int row, int kg) {
  unsigned b = (unsigned)(row * 64 + kg * 16);
  return b ^ (((unsigned)row & 6u) << 3);
}

typedef const __attribute__((address_space(1))) unsigned int gu32_t;
typedef __attribute__((address_space(3))) unsigned int lu32_t;
__device__ __forceinline__ void gload_lds16(const void* g, void* l) {
  __builtin_amdgcn_global_load_lds((gu32_t*)g, (lu32_t*)l, 16, 0, 0);
}

// ---------------------------------------------------------------------------
// Counted-vmcnt depth-2 gl_lds core (verified r9): 128x128 tile, 4 waves,
// K-step 32 (64 B/row f16), 3 LDS buffers of 16 KB (A at +0, B at +8192).
// vmcnt(8) = 2 tiles x 4 loads/wave in flight. Read-side XOR swizzle applied
// by pre-swizzling the per-lane GLOBAL source chunk (both-sides rule).
// ---------------------------------------------------------------------------
template <class P>
__device__ __forceinline__ void stage_tile(const P& prov, char* smem, int buf,
                                           int t, int wave, int l4, int cp) {
  char* lb = smem + buf * 16384;
#pragma unroll
  for (int h = 0; h < 2; h++) {
    int R = wave * 32 + h * 16;
    int row = R + l4;
    int c = cp ^ ((row >> 1) & 3);
    gload_lds16((const char*)prov.a_src(t, row) + c * 16, lb + R * 64);
    gload_lds16((const char*)prov.b_src(t, row) + c * 16, lb + 8192 + R * 64);
  }
}

template <int NT, class P>
__device__ __forceinline__ void gemm_core_cnt(const P& prov, char* smem, f32x4 (&acc)[4][4]) {
  const int tid = threadIdx.x;
  const int lane = tid & 63, wave = tid >> 6;
  const int l4 = lane >> 2, cp = lane & 3;
  const int wm = wave >> 1, wn = wave & 1;
  const int r16 = lane & 15, kg = lane >> 4;

  stage_tile(prov, smem, 0, 0, wave, l4, cp);
  stage_tile(prov, smem, 1, 1, wave, l4, cp);
  stage_tile(prov, smem, 2, 2, wave, l4, cp);

  int buf = 0;
  for (int t = 0; t < NT; t++) {
    asm volatile("s_waitcnt vmcnt(8)" ::: "memory");
    __builtin_amdgcn_s_barrier();
    char* lb = smem + buf * 16384;
    h16x8 af[4], bf[4];
#pragma unroll
    for (int mf = 0; mf < 4; mf++)
      af[mf] = *(const h16x8*)(lb + swzr(wm * 64 + mf * 16 + r16, kg));
#pragma unroll
    for (int nf = 0; nf < 4; nf++)
      bf[nf] = *(const h16x8*)(lb + 8192 + swzr(wn * 64 + nf * 16 + r16, kg));
#pragma unroll
    for (int mf = 0; mf < 4; mf++)
#pragma unroll
      for (int nf = 0; nf < 4; nf++)
        acc[mf][nf] = __builtin_amdgcn_mfma_f32_16x16x32_f16(af[mf], bf[nf], acc[mf][nf], 0, 0, 0);
    asm volatile("s_waitcnt lgkmcnt(0)" ::: "memory");
    __builtin_amdgcn_s_barrier();
    int nt2 = t + 3; if (nt2 >= NT) nt2 = NT - 1;   // clamped restage keeps vmcnt counting uniform
    stage_tile(prov, smem, buf, nt2, wave, l4, cp);
    buf = (buf == 2) ? 0 : buf + 1;
  }
}

// ---------------- providers -------------------------------------------------
struct ProvQK {   // base scores: A=q_h rows i, B=k_h rows j (stride 1024 B)
  const char *ar, *br;
  __device__ __forceinline__ const void* a_src(int t, int row) const {
    return ar + (size_t)row * 1024 + (size_t)t * 64;
  }
  __device__ __forceinline__ const void* b_src(int t, int row) const {
    return br + (size_t)row * 1024 + (size_t)t * 64;
  }
};
struct ProvRel {  // rel scores: A=q_h, B=wk_h band rows (clamped)
  const char *ar, *wk; int tb;
  __device__ __forceinline__ const void* a_src(int t, int row) const {
    return ar + (size_t)row * 1024 + (size_t)t * 64;
  }
  __device__ __forceinline__ const void* b_src(int t, int row) const {
    int tr = tb + row; if (tr > WROWS - 1) tr = WROWS - 1;
    return wk + (size_t)tr * 1024 + (size_t)t * 64;
  }
};

// ---------------- f32 -> f16 bulk convert -----------------------------------
__global__ __launch_bounds__(256) void cvt_f16_k(const float* __restrict__ in,
                                                 _Float16* __restrict__ out, long n8) {
  for (long i = (long)blockIdx.x * 256 + threadIdx.x; i < n8; i += (long)gridDim.x * 256) {
    f32x4 a = ((const f32x4*)in)[i * 2];
    f32x4 b = ((const f32x4*)in)[i * 2 + 1];
    h16x8 h = {(_Float16)a[0], (_Float16)a[1], (_Float16)a[2], (_Float16)a[3],
               (_Float16)b[0], (_Float16)b[1], (_Float16)b[2], (_Float16)b[3]};
    ((h16x8*)out)[i] = h;
  }
}

// ---------------- transpose v [B,N,D] f32 -> vT [B,D,N] f16 ----------------
__global__ __launch_bounds__(256) void transpose_v_k(const float* __restrict__ v,
                                                     _Float16* __restrict__ vT) {
  __shared__ float tile[32][33];
  const int d0 = blockIdx.x * 32, j0 = blockIdx.y * 32, b = blockIdx.z;
  const int tid = threadIdx.x;
#pragma unroll
  for (int rep = 0; rep < 4; rep++) {
    int idx = rep * 256 + tid;
    int rr = idx >> 5, cc = idx & 31;
    tile[rr][cc] = v[((size_t)(b * SEQN + j0 + rr)) * DD + d0 + cc];
  }
  __syncthreads();
#pragma unroll
  for (int rep = 0; rep < 4; rep++) {
    int idx = rep * 256 + tid;
    int rr = idx >> 5, cc = idx & 31;
    vT[((size_t)(b * DD + d0 + rr)) * SEQN + j0 + cc] = (_Float16)tile[cc][rr];
  }
}

// ------------- transpose w_v [4095,512] f32 -> wvT [512,4096] f16 -----------
__global__ __launch_bounds__(256) void transpose_wv_k(const float* __restrict__ wv,
                                                      _Float16* __restrict__ wvT) {
  __shared__ float tile[32][33];
  const int d0 = blockIdx.x * 32, r0 = blockIdx.y * 32;
  const int tid = threadIdx.x;
#pragma unroll
  for (int rep = 0; rep < 4; rep++) {
    int idx = rep * 256 + tid;
    int rr = idx >> 5, cc = idx & 31;
    float val = 0.f;
    if (r0 + rr < WROWS) val = wv[(size_t)(r0 + rr) * DD + d0 + cc];
    tile[rr][cc] = val;
  }
  __syncthreads();
#pragma unroll
  for (int rep = 0; rep < 4; rep++) {
    int idx = rep * 256 + tid;
    int rr = idx >> 5, cc = idx & 31;
    wvT[(size_t)(d0 + rr) * WPAD + r0 + cc] = (_Float16)tile[cc][rr];
  }
}

// ---------------- score kernels: counted-vmcnt gl_lds core ------------------
__global__ __launch_bounds__(256) void score_base2_k(const _Float16* __restrict__ qh,
                                                     const _Float16* __restrict__ kh,
                                                     float* __restrict__ S) {
  __shared__ __align__(16) char smem[49152];
  const int j0 = blockIdx.x * 128, i0 = blockIdx.y * 128, b = blockIdx.z;
  const int tid = threadIdx.x, lane = tid & 63, wave = tid >> 6;
  const int wm = wave >> 1, wn = wave & 1, r16 = lane & 15, kg = lane >> 4;

  f32x4 acc[4][4];
#pragma unroll
  for (int mf = 0; mf < 4; mf++)
#pragma unroll
    for (int nf = 0; nf < 4; nf++) acc[mf][nf] = (f32x4){0.f, 0.f, 0.f, 0.f};

  ProvQK prov{(const char*)(qh + (size_t)(b * SEQN + i0) * DD),
              (const char*)(kh + (size_t)(b * SEQN + j0) * DD)};
  gemm_core_cnt<16>(prov, smem, acc);

#pragma unroll
  for (int mf = 0; mf < 4; mf++)
#pragma unroll
    for (int nf = 0; nf < 4; nf++)
#pragma unroll
      for (int r = 0; r < 4; r++) {
        int ii = wm * 64 + mf * 16 + kg * 4 + r;
        int jj = wn * 64 + nf * 16 + r16;
        S[(size_t)(b * SEQN + i0 + ii) * SEQN + j0 + jj] = acc[mf][nf][r];
      }
}

__global__ __launch_bounds__(256) void score_rel2_k(const _Float16* __restrict__ qh,
                                                    const _Float16* __restrict__ wkh,
                                                    float* __restrict__ S) {
  __shared__ __align__(16) char smem[49152];
  const int z = blockIdx.x, i0 = blockIdx.y * 128, b = blockIdx.z;
  const int tid = threadIdx.x, lane = tid & 63, wave = tid >> 6;
  const int wm = wave >> 1, wn = wave & 1, r16 = lane & 15, kg = lane >> 4;
  const int tmin = SEQN - 128 - i0;

  f32x4 acc[4][4];
#pragma unroll
  for (int mf = 0; mf < 4; mf++)
#pragma unroll
    for (int nf = 0; nf < 4; nf++) acc[mf][nf] = (f32x4){0.f, 0.f, 0.f, 0.f};

  ProvRel prov{(const char*)(qh + (size_t)(b * SEQN + i0) * DD),
               (const char*)wkh, tmin + z * 128};
  gemm_core_cnt<16>(prov, smem, acc);

  // scatter-add: band col bc -> j = bc + i' - 127
#pragma unroll
  for (int mf = 0; mf < 4; mf++)
#pragma unroll
    for (int nf = 0; nf < 4; nf++) {
      int bcg = z * 128 + wn * 64 + nf * 16 + r16;
#pragma unroll
      for (int r = 0; r < 4; r++) {
        int ii = wm * 64 + mf * 16 + kg * 4 + r;
        int j = bcg + ii - 127;
        if (bcg <= 2174 && j >= 0 && j < SEQN)
          S[(size_t)(b * SEQN + i0 + ii) * SEQN + j] += acc[mf][nf][r];
      }
    }
}

// ---------------- softmax over rows of S (in place -> p) --------------------
__global__ __launch_bounds__(256) void softmax_rows_k(float* __restrict__ S) {
  const int wid = threadIdx.x >> 6, lane = threadIdx.x & 63;
  const size_t row = (size_t)blockIdx.x * 4 + wid;
  float* p = S + row * SEQN;
  f32x4 x[8];
  float m = -3.4e38f;
#pragma unroll
  for (int c = 0; c < 8; c++) {
    x[c] = *(const f32x4*)(p + c * 256 + lane * 4);
    m = fmaxf(m, fmaxf(fmaxf(x[c][0], x[c][1]), fmaxf(x[c][2], x[c][3])));
  }
#pragma unroll
  for (int off = 32; off > 0; off >>= 1) m = fmaxf(m, __shfl_xor(m, off));
  float s = 0.f;
#pragma unroll
  for (int c = 0; c < 8; c++)
#pragma unroll
    for (int e = 0; e < 4; e++) {
      x[c][e] = __expf(x[c][e] - m);
      s += x[c][e];
    }
#pragma unroll
  for (int off = 32; off > 0; off >>= 1) s += __shfl_xor(s, off);
  float inv = 1.f / s;
#pragma unroll
  for (int c = 0; c < 8; c++) {
    x[c][0] *= inv; x[c][1] *= inv; x[c][2] *= inv; x[c][3] *= inv;
    *(f32x4*)(p + c * 256 + lane * 4) = x[c];
  }
}

// ------- out = p.v + skew(p).w_v — r8's out_gemm3 verbatim (169us best) -----
// 132 K-steps: t in [0,64) = p.v ; t in [64,132) = skew(p).w_v.
// Reg-prefetch one step ahead; 2x16KB LDS double buffer; 1 barrier/step.
__global__ __launch_bounds__(256) void out_gemm3_k(const float* __restrict__ S,
                                                   const _Float16* __restrict__ vT,
                                                   const _Float16* __restrict__ wvT,
                                                   float* __restrict__ outp) {
  __shared__ __align__(16) char smem[32768];
  // XCD-aware decode: 4 d-tiles sharing (i0,b)'s p rows land on one XCD.
  const int bid = blockIdx.x;
  const int xcd = bid & 7, rr = bid >> 3;
  const int x = rr & 3, s8 = rr >> 2;
  const int sidx = xcd + 8 * s8;             // [0,128): (i-tile, b), bijective
  const int d0 = x * 128, i0 = (sidx & 15) * 128, b = sidx >> 4;
  const int tid = threadIdx.x, lane = tid & 63, wave = tid >> 6;
  const int wm = wave >> 1, wn = wave & 1, r16 = lane & 15, kg = lane >> 4;
  const int tmin = SEQN - 128 - i0;

  const float*    pb = S  + (size_t)(b * SEQN + i0) * SEQN;
  const _Float16* vb = vT + (size_t)(b * DD + d0) * SEQN;
  const _Float16* wb = wvT + (size_t)d0 * WPAD + tmin;

  f32x4 acc[4][4];
#pragma unroll
  for (int mf = 0; mf < 4; mf++)
#pragma unroll
    for (int nf = 0; nf < 4; nf++) acc[mf][nf] = (f32x4){0.f, 0.f, 0.f, 0.f};

  f32x4 ra[4];      // staged A (f32, cvt at LDS-write time)
  h16x4 rbv[4];     // staged B (f16)

  auto LOADREGS = [&](int t) {
    if (t < 64) {
      const int k0 = t * 32;
#pragma unroll
      for (int rep = 0; rep < 4; rep++) {
        int f = rep * 256 + tid, row = f >> 3, c4 = f & 7;
        ra[rep]  = *(const f32x4*)(pb + (size_t)row * SEQN + k0 + c4 * 4);
        rbv[rep] = *(const h16x4*)(vb + (size_t)row * SEQN + k0 + c4 * 4);
      }
    } else {
      const int k0 = (t - 64) * 32;
#pragma unroll
      for (int rep = 0; rep < 4; rep++) {
        int f = rep * 256 + tid, row = f >> 3, c4 = f & 7;
        int jb = k0 + c4 * 4 + row - 127;
        const float* pr = pb + (size_t)row * SEQN;
        f32x4 v4;
#pragma unroll
        for (int e = 0; e < 4; e++) {
          int j = jb + e;
          v4[e] = (j >= 0 && j < SEQN) ? pr[j] : 0.f;
        }
        ra[rep]  = v4;
        rbv[rep] = *(const h16x4*)(wb + (size_t)row * WPAD + k0 + c4 * 4);
      }
    }
  };
  auto WRITE = [&](char* lb) {
#pragma unroll
    for (int rep = 0; rep < 4; rep++) {
      int f = rep * 256 + tid, row = f >> 3, c4 = f & 7;
      h16x4 ha = {(_Float16)ra[rep][0], (_Float16)ra[rep][1],
                  (_Float16)ra[rep][2], (_Float16)ra[rep][3]};
      *(h16x4*)(lb + swzw(row, c4)) = ha;
      *(h16x4*)(lb + 8192 + swzw(row, c4)) = rbv[rep];
    }
  };

  LOADREGS(0);
  WRITE(smem);
  LOADREGS(1);                 // tile 1 pending in regs
  __syncthreads();             // tile 0 visible

  for (int t = 0; t < 132; t++) {
    char* lb = smem + (t & 1) * 16384;
    if (t + 1 < 132) WRITE(smem + ((t + 1) & 1) * 16384);   // WAR-safe
    h16x8 af[4], bf[4];
#pragma unroll
    for (int mf = 0; mf < 4; mf++)
      af[mf] = *(const h16x8*)(lb + swzr(wm * 64 + mf * 16 + r16, kg));
#pragma unroll
    for (int nf = 0; nf < 4; nf++)
      bf[nf] = *(const h16x8*)(lb + 8192 + swzr(wn * 64 + nf * 16 + r16, kg));
    if (t + 2 < 132) LOADREGS(t + 2);                        // issue early
#pragma unroll
    for (int mf = 0; mf < 4; mf++)
#pragma unroll
      for (int nf = 0; nf < 4; nf++)
        acc[mf][nf] = __builtin_amdgcn_mfma_f32_16x16x32_f16(af[mf], bf[nf], acc[mf][nf], 0, 0, 0);
    __syncthreads();
  }

#pragma unroll
  for (int mf = 0; mf < 4; mf++)
#pragma unroll
    for (int nf = 0; nf < 4; nf++)
#pragma unroll
      for (int r = 0; r < 4; r++) {
        int ii = wm * 64 + mf * 16 + kg * 4 + r;
        int dd = wn * 64 + nf * 16 + r16;
        outp[(size_t)(b * SEQN + i0 + ii) * DD + d0 + dd] = acc[mf][nf][r];
      }
}

extern "C" void kernel_launch(void* const* d_in, const int* in_sizes, int n_in,
                              void* d_out, int out_size, void* d_ws, size_t ws_size,
                              hipStream_t stream) {
  const float* q  = (const float*)d_in[0];
  const float* k  = (const float*)d_in[1];
  const float* v  = (const float*)d_in[2];
  const float* wk = (const float*)d_in[3];
  const float* wv = (const float*)d_in[4];

  float* outp = (float*)d_out;
  float* S    = outp + (size_t)NB * SEQN * DD;   // p region of d_out doubles as S

  // ws layout (f16 elems): vT | wvT | qh | kh | wkh = 58.7 MB
  const size_t nVT = (size_t)NB * DD * SEQN;     // 8388608
  const size_t nWV = (size_t)DD * WPAD;          // 2097152
  const size_t nQH = (size_t)NB * SEQN * DD;     // 8388608
  _Float16* vT  = (_Float16*)d_ws;
  _Float16* wvT = vT + nVT;
  _Float16* qh  = wvT + nWV;
  _Float16* kh  = qh + nQH;
  _Float16* wkh = kh + nQH;

  cvt_f16_k<<<dim3(2048), 256, 0, stream>>>(q,  qh,  (long)(nQH / 8));
  cvt_f16_k<<<dim3(2048), 256, 0, stream>>>(k,  kh,  (long)(nQH / 8));
  cvt_f16_k<<<dim3(1024), 256, 0, stream>>>(wk, wkh, (long)((size_t)WROWS * DD / 8));
  transpose_v_k <<<dim3(DD / 32, SEQN / 32, NB), 256, 0, stream>>>(v, vT);
  transpose_wv_k<<<dim3(DD / 32, 128),           256, 0, stream>>>(wv, wvT);

  score_base2_k <<<dim3(SEQN / 128, SEQN / 128, NB), 256, 0, stream>>>(qh, kh, S);
  score_rel2_k  <<<dim3(17, SEQN / 128, NB),         256, 0, stream>>>(qh, wkh, S);
  softmax_rows_k<<<dim3(NB * SEQN / 4),              256, 0, stream>>>(S);
  out_gemm3_k   <<<dim3(512),                        256, 0, stream>>>(S, vT, wvT, outp);
}

// Round 15
// 405.665 us; speedup vs baseline: 1.0713x; 1.0243x over previous
//
#include <hip/hip_runtime.h>

// RelativeAttention B=8, N=2048, D=512, fp32 in, (out[B,N,D], p[B,N,N]) fp32 out.
//
// Round-15: r14 verbatim except out_gemm re-parameterized to BM=256 x BN=128,
// 8 waves (512 thr). Same verified schedule (depth-1 reg prefetch, 2-buffer,
// 1 __syncthreads/step), same swizzle pair, same per-wave 4x4 fragment shape.
// Staging drops 8 -> 6 slots/thread/step (-25% staging instrs); band widens
// to 2304 cols (136 K-steps, +3%); grid 256 blocks = 1/CU exactly.
// Per-output-element MFMA sequence and cvt points unchanged (extra band cols
// are exact +0.0f) -> absmax must be exactly 0.0859375.

#define SEQN 2048
#define DD   512
#define NB   8
#define WROWS 4095   // 2N-1
#define WPAD  4096   // padded row stride for wvT

typedef float     f32x4 __attribute__((ext_vector_type(4)));
typedef _Float16  h16x4 __attribute__((ext_vector_type(4)));
typedef _Float16  h16x8 __attribute__((ext_vector_type(8)));

__device__ __forceinline__ unsigned swzw(int row, int c4) {
  unsigned b = (unsigned)(row * 64 + c4 * 8);
  return b ^ (((unsigned)row & 6u) << 3);
}
__device__ __forceinline__ unsigned swzr(int row, int kg) {
  unsigned b = (unsigned)(row * 64 + kg * 16);
  return b ^ (((unsigned)row & 6u) << 3);
}

typedef const __attribute__((address_space(1))) unsigned int gu32_t;
typedef __attribute__((address_space(3))) unsigned int lu32_t;
__device__ __forceinline__ void gload_lds16(const void* g, void* l) {
  __builtin_amdgcn_global_load_lds((gu32_t*)g, (lu32_t*)l, 16, 0, 0);
}

// ---------------------------------------------------------------------------
// Counted-vmcnt depth-2 gl_lds core (verified r9) — scores.
// ---------------------------------------------------------------------------
template <class P>
__device__ __forceinline__ void stage_tile(const P& prov, char* smem, int buf,
                                           int t, int wave, int l4, int cp) {
  char* lb = smem + buf * 16384;
#pragma unroll
  for (int h = 0; h < 2; h++) {
    int R = wave * 32 + h * 16;
    int row = R + l4;
    int c = cp ^ ((row >> 1) & 3);
    gload_lds16((const char*)prov.a_src(t, row) + c * 16, lb + R * 64);
    gload_lds16((const char*)prov.b_src(t, row) + c * 16, lb + 8192 + R * 64);
  }
}

template <int NT, class P>
__device__ __forceinline__ void gemm_core_cnt(const P& prov, char* smem, f32x4 (&acc)[4][4]) {
  const int tid = threadIdx.x;
  const int lane = tid & 63, wave = tid >> 6;
  const int l4 = lane >> 2, cp = lane & 3;
  const int wm = wave >> 1, wn = wave & 1;
  const int r16 = lane & 15, kg = lane >> 4;

  stage_tile(prov, smem, 0, 0, wave, l4, cp);
  stage_tile(prov, smem, 1, 1, wave, l4, cp);
  stage_tile(prov, smem, 2, 2, wave, l4, cp);

  int buf = 0;
  for (int t = 0; t < NT; t++) {
    asm volatile("s_waitcnt vmcnt(8)" ::: "memory");
    __builtin_amdgcn_s_barrier();
    char* lb = smem + buf * 16384;
    h16x8 af[4], bf[4];
#pragma unroll
    for (int mf = 0; mf < 4; mf++)
      af[mf] = *(const h16x8*)(lb + swzr(wm * 64 + mf * 16 + r16, kg));
#pragma unroll
    for (int nf = 0; nf < 4; nf++)
      bf[nf] = *(const h16x8*)(lb + 8192 + swzr(wn * 64 + nf * 16 + r16, kg));
#pragma unroll
    for (int mf = 0; mf < 4; mf++)
#pragma unroll
      for (int nf = 0; nf < 4; nf++)
        acc[mf][nf] = __builtin_amdgcn_mfma_f32_16x16x32_f16(af[mf], bf[nf], acc[mf][nf], 0, 0, 0);
    asm volatile("s_waitcnt lgkmcnt(0)" ::: "memory");
    __builtin_amdgcn_s_barrier();
    int nt2 = t + 3; if (nt2 >= NT) nt2 = NT - 1;   // clamped restage keeps vmcnt counting uniform
    stage_tile(prov, smem, buf, nt2, wave, l4, cp);
    buf = (buf == 2) ? 0 : buf + 1;
  }
}

// ---------------- providers -------------------------------------------------
struct ProvQK {   // base scores: A=q_h rows i, B=k_h rows j (stride 1024 B)
  const char *ar, *br;
  __device__ __forceinline__ const void* a_src(int t, int row) const {
    return ar + (size_t)row * 1024 + (size_t)t * 64;
  }
  __device__ __forceinline__ const void* b_src(int t, int row) const {
    return br + (size_t)row * 1024 + (size_t)t * 64;
  }
};
struct ProvRel {  // rel scores: A=q_h, B=wk_h band rows (clamped)
  const char *ar, *wk; int tb;
  __device__ __forceinline__ const void* a_src(int t, int row) const {
    return ar + (size_t)row * 1024 + (size_t)t * 64;
  }
  __device__ __forceinline__ const void* b_src(int t, int row) const {
    int tr = tb + row; if (tr > WROWS - 1) tr = WROWS - 1;
    return wk + (size_t)tr * 1024 + (size_t)t * 64;
  }
};

// ---------------- f32 -> f16 bulk convert -----------------------------------
__global__ __launch_bounds__(256) void cvt_f16_k(const float* __restrict__ in,
                                                 _Float16* __restrict__ out, long n8) {
  for (long i = (long)blockIdx.x * 256 + threadIdx.x; i < n8; i += (long)gridDim.x * 256) {
    f32x4 a = ((const f32x4*)in)[i * 2];
    f32x4 b = ((const f32x4*)in)[i * 2 + 1];
    h16x8 h = {(_Float16)a[0], (_Float16)a[1], (_Float16)a[2], (_Float16)a[3],
               (_Float16)b[0], (_Float16)b[1], (_Float16)b[2], (_Float16)b[3]};
    ((h16x8*)out)[i] = h;
  }
}

// ---------------- transpose v [B,N,D] f32 -> vT [B,D,N] f16 ----------------
__global__ __launch_bounds__(256) void transpose_v_k(const float* __restrict__ v,
                                                     _Float16* __restrict__ vT) {
  __shared__ float tile[32][33];
  const int d0 = blockIdx.x * 32, j0 = blockIdx.y * 32, b = blockIdx.z;
  const int tid = threadIdx.x;
#pragma unroll
  for (int rep = 0; rep < 4; rep++) {
    int idx = rep * 256 + tid;
    int rr = idx >> 5, cc = idx & 31;
    tile[rr][cc] = v[((size_t)(b * SEQN + j0 + rr)) * DD + d0 + cc];
  }
  __syncthreads();
#pragma unroll
  for (int rep = 0; rep < 4; rep++) {
    int idx = rep * 256 + tid;
    int rr = idx >> 5, cc = idx & 31;
    vT[((size_t)(b * DD + d0 + rr)) * SEQN + j0 + cc] = (_Float16)tile[cc][rr];
  }
}

// ------------- transpose w_v [4095,512] f32 -> wvT [512,4096] f16 -----------
__global__ __launch_bounds__(256) void transpose_wv_k(const float* __restrict__ wv,
                                                      _Float16* __restrict__ wvT) {
  __shared__ float tile[32][33];
  const int d0 = blockIdx.x * 32, r0 = blockIdx.y * 32;
  const int tid = threadIdx.x;
#pragma unroll
  for (int rep = 0; rep < 4; rep++) {
    int idx = rep * 256 + tid;
    int rr = idx >> 5, cc = idx & 31;
    float val = 0.f;
    if (r0 + rr < WROWS) val = wv[(size_t)(r0 + rr) * DD + d0 + cc];
    tile[rr][cc] = val;
  }
  __syncthreads();
#pragma unroll
  for (int rep = 0; rep < 4; rep++) {
    int idx = rep * 256 + tid;
    int rr = idx >> 5, cc = idx & 31;
    wvT[(size_t)(d0 + rr) * WPAD + r0 + cc] = (_Float16)tile[cc][rr];
  }
}

// ---------------- score kernels: counted-vmcnt gl_lds core ------------------
__global__ __launch_bounds__(256) void score_base2_k(const _Float16* __restrict__ qh,
                                                     const _Float16* __restrict__ kh,
                                                     float* __restrict__ S) {
  __shared__ __align__(16) char smem[49152];
  const int j0 = blockIdx.x * 128, i0 = blockIdx.y * 128, b = blockIdx.z;
  const int tid = threadIdx.x, lane = tid & 63, wave = tid >> 6;
  const int wm = wave >> 1, wn = wave & 1, r16 = lane & 15, kg = lane >> 4;

  f32x4 acc[4][4];
#pragma unroll
  for (int mf = 0; mf < 4; mf++)
#pragma unroll
    for (int nf = 0; nf < 4; nf++) acc[mf][nf] = (f32x4){0.f, 0.f, 0.f, 0.f};

  ProvQK prov{(const char*)(qh + (size_t)(b * SEQN + i0) * DD),
              (const char*)(kh + (size_t)(b * SEQN + j0) * DD)};
  gemm_core_cnt<16>(prov, smem, acc);

#pragma unroll
  for (int mf = 0; mf < 4; mf++)
#pragma unroll
    for (int nf = 0; nf < 4; nf++)
#pragma unroll
      for (int r = 0; r < 4; r++) {
        int ii = wm * 64 + mf * 16 + kg * 4 + r;
        int jj = wn * 64 + nf * 16 + r16;
        S[(size_t)(b * SEQN + i0 + ii) * SEQN + j0 + jj] = acc[mf][nf][r];
      }
}

__global__ __launch_bounds__(256) void score_rel2_k(const _Float16* __restrict__ qh,
                                                    const _Float16* __restrict__ wkh,
                                                    float* __restrict__ S) {
  __shared__ __align__(16) char smem[49152];
  const int z = blockIdx.x, i0 = blockIdx.y * 128, b = blockIdx.z;
  const int tid = threadIdx.x, lane = tid & 63, wave = tid >> 6;
  const int wm = wave >> 1, wn = wave & 1, r16 = lane & 15, kg = lane >> 4;
  const int tmin = SEQN - 128 - i0;

  f32x4 acc[4][4];
#pragma unroll
  for (int mf = 0; mf < 4; mf++)
#pragma unroll
    for (int nf = 0; nf < 4; nf++) acc[mf][nf] = (f32x4){0.f, 0.f, 0.f, 0.f};

  ProvRel prov{(const char*)(qh + (size_t)(b * SEQN + i0) * DD),
               (const char*)wkh, tmin + z * 128};
  gemm_core_cnt<16>(prov, smem, acc);

  // scatter-add: band col bc -> j = bc + i' - 127
#pragma unroll
  for (int mf = 0; mf < 4; mf++)
#pragma unroll
    for (int nf = 0; nf < 4; nf++) {
      int bcg = z * 128 + wn * 64 + nf * 16 + r16;
#pragma unroll
      for (int r = 0; r < 4; r++) {
        int ii = wm * 64 + mf * 16 + kg * 4 + r;
        int j = bcg + ii - 127;
        if (bcg <= 2174 && j >= 0 && j < SEQN)
          S[(size_t)(b * SEQN + i0 + ii) * SEQN + j] += acc[mf][nf][r];
      }
    }
}

// ---------------- softmax over rows of S (in place -> p) --------------------
__global__ __launch_bounds__(256) void softmax_rows_k(float* __restrict__ S) {
  const int wid = threadIdx.x >> 6, lane = threadIdx.x & 63;
  const size_t row = (size_t)blockIdx.x * 4 + wid;
  float* p = S + row * SEQN;
  f32x4 x[8];
  float m = -3.4e38f;
#pragma unroll
  for (int c = 0; c < 8; c++) {
    x[c] = *(const f32x4*)(p + c * 256 + lane * 4);
    m = fmaxf(m, fmaxf(fmaxf(x[c][0], x[c][1]), fmaxf(x[c][2], x[c][3])));
  }
#pragma unroll
  for (int off = 32; off > 0; off >>= 1) m = fmaxf(m, __shfl_xor(m, off));
  float s = 0.f;
#pragma unroll
  for (int c = 0; c < 8; c++)
#pragma unroll
    for (int e = 0; e < 4; e++) {
      x[c][e] = __expf(x[c][e] - m);
      s += x[c][e];
    }
#pragma unroll
  for (int off = 32; off > 0; off >>= 1) s += __shfl_xor(s, off);
  float inv = 1.f / s;
#pragma unroll
  for (int c = 0; c < 8; c++) {
    x[c][0] *= inv; x[c][1] *= inv; x[c][2] *= inv; x[c][3] *= inv;
    *(f32x4*)(p + c * 256 + lane * 4) = x[c];
  }
}

// ------- out = p.v + skew(p).w_v — BM=256 x BN=128, 8 waves ----------------
// 136 K-steps: t in [0,64) = p.v ; t in [64,136) = skew(p).w_v (band 2304,
// j = bc + row - 255; clean t in [72,128)). Schedule = r8's out_gemm3
// (reg-prefetch 1 step, 2 x 24KB LDS buffers, 1 __syncthreads/step).
// Staging: 4 A-slots + 2 B-slots per thread per step.
__global__ __launch_bounds__(512) void out_gemm9_k(const float* __restrict__ S,
                                                   const _Float16* __restrict__ vT,
                                                   const _Float16* __restrict__ wvT,
                                                   float* __restrict__ outp) {
  __shared__ __align__(16) char smem[49152];
  // decode: 256 blocks = 4 d-tiles x 64 row-tiles; same-rt blocks co-XCD.
  const int bid = blockIdx.x;
  const int xcd = bid & 7, rr = bid >> 3;
  const int x = rr & 3, s8 = rr >> 2;
  const int rt = xcd + 8 * s8;               // [0,64): row-tile, bijective
  const int d0 = x * 128, b = rt >> 3, i0 = (rt & 7) * 256;
  const int tid = threadIdx.x, lane = tid & 63, wave = tid >> 6;
  const int wm = wave >> 1, wn = wave & 1, r16 = lane & 15, kg = lane >> 4;
  const int tmin = SEQN - 256 - i0;          // first band row (>=0, <=1792)

  const float*    pb = S  + (size_t)(b * SEQN + i0) * SEQN;
  const _Float16* vb = vT + (size_t)(b * DD + d0) * SEQN;
  const _Float16* wb = wvT + (size_t)d0 * WPAD + tmin;

  f32x4 acc[4][4];
#pragma unroll
  for (int mf = 0; mf < 4; mf++)
#pragma unroll
    for (int nf = 0; nf < 4; nf++) acc[mf][nf] = (f32x4){0.f, 0.f, 0.f, 0.f};

  f32x4 ra[4];      // 4 A-slots (f32, cvt at LDS-write)
  h16x4 rbv[2];     // 2 B-slots (f16)

  auto LOADREGS = [&](int t) {
    if (t < 64) {
      const int k0 = t * 32;
#pragma unroll
      for (int rep = 0; rep < 4; rep++) {           // A: 2048 slots / 512 thr
        int f = rep * 512 + tid, row = f >> 3, c4 = f & 7;
        ra[rep] = *(const f32x4*)(pb + (size_t)row * SEQN + k0 + c4 * 4);
      }
#pragma unroll
      for (int rep = 0; rep < 2; rep++) {           // B: 1024 slots / 512 thr
        int f = rep * 512 + tid, row = f >> 3, c4 = f & 7;
        rbv[rep] = *(const h16x4*)(vb + (size_t)row * SEQN + k0 + c4 * 4);
      }
    } else {
      const int k0 = (t - 64) * 32;
      const bool clean = (t >= 72) && (t < 128);    // j provably in [0,2048)
#pragma unroll
      for (int rep = 0; rep < 4; rep++) {
        int f = rep * 512 + tid, row = f >> 3, c4 = f & 7;
        int jb = k0 + c4 * 4 + row - 255;
        const float* pr = pb + (size_t)row * SEQN;
        f32x4 v4;
        if (clean) {
          __builtin_memcpy(&v4, pr + jb, 16);       // unpredicated, 4B-aligned
        } else {
#pragma unroll
          for (int e = 0; e < 4; e++) {
            int j = jb + e;
            v4[e] = (j >= 0 && j < SEQN) ? pr[j] : 0.f;
          }
        }
        ra[rep] = v4;
      }
#pragma unroll
      for (int rep = 0; rep < 2; rep++) {
        int f = rep * 512 + tid, row = f >> 3, c4 = f & 7;
        rbv[rep] = *(const h16x4*)(wb + (size_t)row * WPAD + k0 + c4 * 4);
      }
    }
  };
  auto WRITE = [&](char* lb) {
#pragma unroll
    for (int rep = 0; rep < 4; rep++) {             // A region [0, 16384)
      int f = rep * 512 + tid, row = f >> 3, c4 = f & 7;
      h16x4 ha = {(_Float16)ra[rep][0], (_Float16)ra[rep][1],
                  (_Float16)ra[rep][2], (_Float16)ra[rep][3]};
      *(h16x4*)(lb + swzw(row, c4)) = ha;
    }
#pragma unroll
    for (int rep = 0; rep < 2; rep++) {             // B region [16384, 24576)
      int f = rep * 512 + tid, row = f >> 3, c4 = f & 7;
      *(h16x4*)(lb + 16384 + swzw(row, c4)) = rbv[rep];
    }
  };

  LOADREGS(0);
  WRITE(smem);
  LOADREGS(1);                 // tile 1 pending in regs
  __syncthreads();             // tile 0 visible

  for (int t = 0; t < 136; t++) {
    char* lb = smem + (t & 1) * 24576;
    if (t + 1 < 136) WRITE(smem + ((t + 1) & 1) * 24576);   // WAR-safe
    h16x8 af[4], bf[4];
#pragma unroll
    for (int mf = 0; mf < 4; mf++)
      af[mf] = *(const h16x8*)(lb + swzr(wm * 64 + mf * 16 + r16, kg));
#pragma unroll
    for (int nf = 0; nf < 4; nf++)
      bf[nf] = *(const h16x8*)(lb + 16384 + swzr(wn * 64 + nf * 16 + r16, kg));
    if (t + 2 < 136) LOADREGS(t + 2);                        // issue early
#pragma unroll
    for (int mf = 0; mf < 4; mf++)
#pragma unroll
      for (int nf = 0; nf < 4; nf++)
        acc[mf][nf] = __builtin_amdgcn_mfma_f32_16x16x32_f16(af[mf], bf[nf], acc[mf][nf], 0, 0, 0);
    __syncthreads();
  }

#pragma unroll
  for (int mf = 0; mf < 4; mf++)
#pragma unroll
    for (int nf = 0; nf < 4; nf++)
#pragma unroll
      for (int r = 0; r < 4; r++) {
        int ii = wm * 64 + mf * 16 + kg * 4 + r;              // [0,256)
        int dd = wn * 64 + nf * 16 + r16;                     // [0,128)
        outp[(size_t)(b * SEQN + i0 + ii) * DD + d0 + dd] = acc[mf][nf][r];
      }
}

extern "C" void kernel_launch(void* const* d_in, const int* in_sizes, int n_in,
                              void* d_out, int out_size, void* d_ws, size_t ws_size,
                              hipStream_t stream) {
  const float* q  = (const float*)d_in[0];
  const float* k  = (const float*)d_in[1];
  const float* v  = (const float*)d_in[2];
  const float* wk = (const float*)d_in[3];
  const float* wv = (const float*)d_in[4];

  float* outp = (float*)d_out;
  float* S    = outp + (size_t)NB * SEQN * DD;   // p region of d_out doubles as S

  // ws layout (f16 elems): vT | wvT | qh | kh | wkh = 58.7 MB
  const size_t nVT = (size_t)NB * DD * SEQN;     // 8388608
  const size_t nWV = (size_t)DD * WPAD;          // 2097152
  const size_t nQH = (size_t)NB * SEQN * DD;     // 8388608
  _Float16* vT  = (_Float16*)d_ws;
  _Float16* wvT = vT + nVT;
  _Float16* qh  = wvT + nWV;
  _Float16* kh  = qh + nQH;
  _Float16* wkh = kh + nQH;

  cvt_f16_k<<<dim3(2048), 256, 0, stream>>>(q,  qh,  (long)(nQH / 8));
  cvt_f16_k<<<dim3(2048), 256, 0, stream>>>(k,  kh,  (long)(nQH / 8));
  cvt_f16_k<<<dim3(1024), 256, 0, stream>>>(wk, wkh, (long)((size_t)WROWS * DD / 8));
  transpose_v_k <<<dim3(DD / 32, SEQN / 32, NB), 256, 0, stream>>>(v, vT);
  transpose_wv_k<<<dim3(DD / 32, 128),           256, 0, stream>>>(wv, wvT);

  score_base2_k <<<dim3(SEQN / 128, SEQN / 128, NB), 256, 0, stream>>>(qh, kh, S);
  score_rel2_k  <<<dim3(17, SEQN / 128, NB),         256, 0, stream>>>(qh, wkh, S);
  softmax_rows_k<<<dim3(NB * SEQN / 4),              256, 0, stream>>>(S);
  out_gemm9_k   <<<dim3(256),                        512, 0, stream>>>(S, vT, wvT, outp);
}